// Round 1
// baseline (500.997 us; speedup 1.0000x reference)
//
#include <hip/hip_runtime.h>
#include <math.h>

#define HID 128
#define INDIM 64

// ---------------- small setup kernels ----------------

__global__ __launch_bounds__(256) void k_init(int* cnt, float* pooled, int* flag, int N, int PB) {
    int i = blockIdx.x * 256 + threadIdx.x;
    if (i < N) cnt[i] = 0;
    if (i < PB) pooled[i] = 0.f;
    if (i == 0) *flag = 0;
}

// Detect whether edge_index arrived as int32 (flag=1) or int64 (flag=0).
// int64 little-endian: high words (odd int32 indices) of the first 256 entries are all 0
// (values in [0, 20000)). int32 layout: these positions hold random src indices.
__global__ __launch_bounds__(256) void k_detect(const int* ei, int* flag) {
    int t = threadIdx.x;
    if (ei[2 * t + 1] != 0) atomicOr(flag, 1);
}

__global__ __launch_bounds__(256) void k_norm_edges(const int* ei, const int* flag,
                                                    int* src, int* dst, int E) {
    int e = blockIdx.x * 256 + threadIdx.x;
    if (e >= E) return;
    if (*flag) {  // int32 layout: [2][E]
        src[e] = ei[e];
        dst[e] = ei[(size_t)E + e];
    } else {      // int64 layout: low word at 2*e
        src[e] = ei[2 * (size_t)e];
        dst[e] = ei[2 * (size_t)E + 2 * (size_t)e];
    }
}

__global__ __launch_bounds__(256) void k_count(const int* __restrict__ dst, int* cnt, int E) {
    int e = blockIdx.x * 256 + threadIdx.x;
    if (e < E) atomicAdd(&cnt[dst[e]], 1);
}

// Single-block: dis = rsqrt(cnt+1); exclusive scan cnt -> row_ptr; zero fillcnt.
__global__ __launch_bounds__(256) void k_scan(const int* __restrict__ cnt, int* row_ptr,
                                              float* dis, int* fillcnt, int N) {
    __shared__ int part[256];
    __shared__ int spart[256];
    int t = threadIdx.x;
    int chunk = (N + 255) >> 8;
    int lo = t * chunk; if (lo > N) lo = N;
    int hi = lo + chunk; if (hi > N) hi = N;
    int s = 0;
    for (int i = lo; i < hi; i++) s += cnt[i];
    part[t] = s;
    __syncthreads();
    if (t == 0) {
        int acc = 0;
        for (int i = 0; i < 256; i++) { spart[i] = acc; acc += part[i]; }
        row_ptr[N] = acc;
    }
    __syncthreads();
    int acc = spart[t];
    for (int i = lo; i < hi; i++) {
        row_ptr[i] = acc;
        acc += cnt[i];
        dis[i] = rsqrtf((float)(cnt[i] + 1));
        fillcnt[i] = 0;
    }
}

__global__ __launch_bounds__(256) void k_fill(const int* __restrict__ src, const int* __restrict__ dst,
                                              const int* __restrict__ row_ptr, int* fillcnt,
                                              int* col, int E) {
    int e = blockIdx.x * 256 + threadIdx.x;
    if (e >= E) return;
    int d = dst[e];
    int p = row_ptr[d] + atomicAdd(&fillcnt[d], 1);
    col[p] = src[e];
}

// ---------------- GEMM: H[outrow][c] = sum_k A[r][k] * W[k][c] ----------------
// block = 256 threads, 16 rows/block; wave w handles rows w, w+4, w+8, w+12; lane c -> cols c, c+64.
// REMAP: input rows r = b*N+n, output rows n*B+b (so gather reads are [n][b][c]-contiguous).
template <int K, bool REMAP>
__global__ __launch_bounds__(256) void k_gemm(const float* __restrict__ A, const float* __restrict__ W,
                                              float* __restrict__ Hout, int N, int B) {
    __shared__ float sW[64][HID];
    __shared__ float sX[16][K];
    int t = threadIdx.x;
    long rbase = (long)blockIdx.x * 16;
    for (int i = t; i < 16 * K; i += 256) {
        int rr = i / K, kk = i - rr * K;
        sX[rr][kk] = A[(rbase + rr) * (long)K + kk];
    }
    int c = t & 63, w = t >> 6;
    float acc[4][2] = {};
    for (int kb = 0; kb < K; kb += 64) {
        __syncthreads();
        for (int i = t; i < 64 * HID; i += 256)
            sW[i >> 7][i & 127] = W[(size_t)(kb + (i >> 7)) * HID + (i & 127)];
        __syncthreads();
#pragma unroll
        for (int k = 0; k < 64; k += 4) {
            float w0[4], w1[4];
#pragma unroll
            for (int kk = 0; kk < 4; kk++) { w0[kk] = sW[k + kk][c]; w1[kk] = sW[k + kk][c + 64]; }
#pragma unroll
            for (int i = 0; i < 4; i++) {
                float4 xv = *(const float4*)&sX[w + 4 * i][kb + k];
                acc[i][0] = fmaf(xv.x, w0[0], acc[i][0]);
                acc[i][1] = fmaf(xv.x, w1[0], acc[i][1]);
                acc[i][0] = fmaf(xv.y, w0[1], acc[i][0]);
                acc[i][1] = fmaf(xv.y, w1[1], acc[i][1]);
                acc[i][0] = fmaf(xv.z, w0[2], acc[i][0]);
                acc[i][1] = fmaf(xv.z, w1[2], acc[i][1]);
                acc[i][0] = fmaf(xv.w, w0[3], acc[i][0]);
                acc[i][1] = fmaf(xv.w, w1[3], acc[i][1]);
            }
        }
    }
#pragma unroll
    for (int i = 0; i < 4; i++) {
        long r = rbase + w + 4 * i;
        long orow;
        if (REMAP) { long b = r / N; long n = r - b * N; orow = n * (long)B + b; }
        else orow = r;
        Hout[orow * HID + c] = acc[i][0];
        Hout[orow * HID + c + 64] = acc[i][1];
    }
}

// ---------------- gather (scatter-as-gather via CSR), layer 1: writes relu(sum + b1) ----------------
// block = one dst node n; wave = batch b; lane c -> channels c, c+64. h layout [n][b][c].
__global__ __launch_bounds__(256) void k_gather1(const float* __restrict__ h, const int* __restrict__ row_ptr,
                                                 const int* __restrict__ col, const float* __restrict__ dis,
                                                 const float* __restrict__ bias, float* __restrict__ xout,
                                                 int N, int B) {
    int n = blockIdx.x;
    int b = threadIdx.x >> 6;
    int c = threadIdx.x & 63;
    float dn = dis[n];
    int beg = row_ptr[n], end = row_ptr[n + 1];
    const float* hn = h + ((size_t)n * B + b) * HID;
    float sl = dn * dn;  // self-loop norm
    float a0 = hn[c] * sl, a1 = hn[c + 64] * sl;
    for (int e = beg; e < end; e++) {
        int s = col[e];
        float wgt = dis[s] * dn;
        const float* hs = h + ((size_t)s * B + b) * HID;
        a0 = fmaf(hs[c], wgt, a0);
        a1 = fmaf(hs[c + 64], wgt, a1);
    }
    float* xr = xout + ((size_t)n * B + b) * HID;
    xr[c]      = fmaxf(a0 + bias[c], 0.f);
    xr[c + 64] = fmaxf(a1 + bias[c + 64], 0.f);
}

// ---------------- layer-2 gather fused with mean-pool: never materializes x2 ----------------
__global__ __launch_bounds__(256) void k_gather2_pool(const float* __restrict__ h, const int* __restrict__ row_ptr,
                                                      const int* __restrict__ col, const float* __restrict__ dis,
                                                      const float* __restrict__ bias, float* __restrict__ pooled,
                                                      int N, int B, float invN) {
    int b = threadIdx.x >> 6;
    int c = threadIdx.x & 63;
    float p0 = 0.f, p1 = 0.f;
    for (int n = blockIdx.x; n < N; n += gridDim.x) {
        float dn = dis[n];
        int beg = row_ptr[n], end = row_ptr[n + 1];
        const float* hn = h + ((size_t)n * B + b) * HID;
        float sl = dn * dn;
        float a0 = hn[c] * sl, a1 = hn[c + 64] * sl;
        for (int e = beg; e < end; e++) {
            int s = col[e];
            float wgt = dis[s] * dn;
            const float* hs = h + ((size_t)s * B + b) * HID;
            a0 = fmaf(hs[c], wgt, a0);
            a1 = fmaf(hs[c + 64], wgt, a1);
        }
        p0 += fmaxf(a0 + bias[c], 0.f);
        p1 += fmaxf(a1 + bias[c + 64], 0.f);
    }
    atomicAdd(&pooled[b * HID + c], p0 * invN);
    atomicAdd(&pooled[b * HID + c + 64], p1 * invN);
}

// ---------------- head: mu = [pooled, af] @ fc_w + fc_b ; sigma = exp(sigma_param) ----------------
__global__ __launch_bounds__(64) void k_head(const float* __restrict__ pooled, const float* __restrict__ af,
                                             const float* __restrict__ fcw, const float* __restrict__ fcb,
                                             const float* __restrict__ sig, float* __restrict__ out, int B) {
    int t = threadIdx.x;
    if (t >= B * 16) return;
    int b = t / 16, o = t - b * 16;
    float acc = fcb[o];
    for (int c = 0; c < HID; c++) acc = fmaf(pooled[b * HID + c], fcw[c * 16 + o], acc);
    acc = fmaf(af[b], fcw[HID * 16 + o], acc);
    out[b * 16 + o] = acc;                       // mu
    out[B * 16 + b * 16 + o] = expf(sig[o]);     // sigma
}

// ---------------- launch ----------------

extern "C" void kernel_launch(void* const* d_in, const int* in_sizes, int n_in,
                              void* d_out, int out_size, void* d_ws, size_t ws_size,
                              hipStream_t stream) {
    const float* x   = (const float*)d_in[0];
    const float* af  = (const float*)d_in[1];
    const int*   ei  = (const int*)d_in[2];
    const float* W1  = (const float*)d_in[3];
    const float* b1  = (const float*)d_in[4];
    const float* W2  = (const float*)d_in[5];
    const float* b2  = (const float*)d_in[6];
    const float* fcw = (const float*)d_in[7];
    const float* fcb = (const float*)d_in[8];
    const float* sig = (const float*)d_in[9];

    int B = in_sizes[1];                 // 4
    int E = in_sizes[2] / 2;             // 320000
    int N = in_sizes[0] / (B * INDIM);   // 20000
    int nrows = B * N;                   // 80000

    char* p = (char*)d_ws;
    auto alloc = [&](size_t bytes) { void* r = (void*)p; p += (bytes + 255) & ~(size_t)255; return r; };
    int*   cnt     = (int*)alloc((size_t)N * 4);
    int*   fillcnt = (int*)alloc((size_t)N * 4);
    int*   row_ptr = (int*)alloc((size_t)(N + 1) * 4);
    int*   colA    = (int*)alloc((size_t)E * 4);
    int*   srcA    = (int*)alloc((size_t)E * 4);
    int*   dstA    = (int*)alloc((size_t)E * 4);
    float* dis     = (float*)alloc((size_t)N * 4);
    float* pooled  = (float*)alloc((size_t)B * HID * 4);
    int*   flag    = (int*)alloc(256);
    float* hA      = (float*)alloc((size_t)nrows * HID * 4);  // 41 MB
    float* xB      = (float*)alloc((size_t)nrows * HID * 4);  // 41 MB
    (void)ws_size;

    int gN = (N + 255) / 256;
    int gE = (E + 255) / 256;

    k_init<<<gN, 256, 0, stream>>>(cnt, pooled, flag, N, B * HID);
    k_detect<<<1, 256, 0, stream>>>(ei, flag);
    k_norm_edges<<<gE, 256, 0, stream>>>(ei, flag, srcA, dstA, E);
    k_count<<<gE, 256, 0, stream>>>(dstA, cnt, E);
    k_scan<<<1, 256, 0, stream>>>(cnt, row_ptr, dis, fillcnt, N);
    k_fill<<<gE, 256, 0, stream>>>(srcA, dstA, row_ptr, fillcnt, colA, E);

    // layer 1: h = x @ W1  (output remapped to [n][b][c])
    k_gemm<INDIM, true><<<nrows / 16, 256, 0, stream>>>(x, W1, hA, N, B);
    k_gather1<<<N, 64 * B, 0, stream>>>(hA, row_ptr, colA, dis, b1, xB, N, B);

    // layer 2: h2 = x1 @ W2  (rows already (n,b))
    k_gemm<HID, false><<<nrows / 16, 256, 0, stream>>>(xB, W2, hA, N, B);
    k_gather2_pool<<<1024, 64 * B, 0, stream>>>(hA, row_ptr, colA, dis, b2, pooled, N, B, 1.0f / (float)N);

    k_head<<<1, 64, 0, stream>>>(pooled, af, fcw, fcb, sig, (float*)d_out, B);
}

// Round 2
// 318.889 us; speedup vs baseline: 1.5711x; 1.5711x over previous
//
#include <hip/hip_runtime.h>
#include <math.h>

#define HID 128
#define INDIM 64
#define NSH 16   // pooled shadow copies (atomic contention spread)

typedef unsigned int uint;
typedef unsigned short ushort;

static __device__ inline float bf2f(uint h) { return __uint_as_float(h << 16); }
static __device__ inline ushort f2bf(float f) {
    uint u = __float_as_uint(f);
    return (ushort)((u + 0x7fff + ((u >> 16) & 1)) >> 16);  // RNE
}

// ---------------- small setup kernels ----------------

__global__ __launch_bounds__(256) void k_init(int* cnt, float* pooledS, int* flag, int N, int PB) {
    int i = blockIdx.x * 256 + threadIdx.x;
    if (i < N) cnt[i] = 0;
    if (i < PB) pooledS[i] = 0.f;
    if (i == 0) *flag = 0;
}

// int32 vs int64 edge_index detection (int64 LE: high words of small values are 0)
__global__ __launch_bounds__(256) void k_detect(const int* ei, int* flag) {
    int t = threadIdx.x;
    if (ei[2 * t + 1] != 0) atomicOr(flag, 1);
}

__global__ __launch_bounds__(256) void k_norm_edges(const int* ei, const int* flag,
                                                    int* src, int* dst, int E) {
    int e = blockIdx.x * 256 + threadIdx.x;
    if (e >= E) return;
    if (*flag) { src[e] = ei[e]; dst[e] = ei[(size_t)E + e]; }
    else       { src[e] = ei[2 * (size_t)e]; dst[e] = ei[2 * (size_t)E + 2 * (size_t)e]; }
}

__global__ __launch_bounds__(256) void k_count(const int* __restrict__ dst, int* cnt, int E) {
    int e = blockIdx.x * 256 + threadIdx.x;
    if (e < E) atomicAdd(&cnt[dst[e]], 1);
}

__global__ __launch_bounds__(256) void k_scan(const int* __restrict__ cnt, int* row_ptr,
                                              float* dis, int* fillcnt, int N) {
    __shared__ int part[256];
    __shared__ int spart[256];
    int t = threadIdx.x;
    int chunk = (N + 255) >> 8;
    int lo = t * chunk; if (lo > N) lo = N;
    int hi = lo + chunk; if (hi > N) hi = N;
    int s = 0;
    for (int i = lo; i < hi; i++) s += cnt[i];
    part[t] = s;
    __syncthreads();
    if (t == 0) {
        int acc = 0;
        for (int i = 0; i < 256; i++) { spart[i] = acc; acc += part[i]; }
        row_ptr[N] = acc;
    }
    __syncthreads();
    int acc = spart[t];
    for (int i = lo; i < hi; i++) {
        row_ptr[i] = acc;
        acc += cnt[i];
        dis[i] = rsqrtf((float)(cnt[i] + 1));
        fillcnt[i] = 0;
    }
}

__global__ __launch_bounds__(256) void k_fill(const int* __restrict__ src, const int* __restrict__ dst,
                                              const int* __restrict__ row_ptr, int* fillcnt,
                                              int* col, int E) {
    int e = blockIdx.x * 256 + threadIdx.x;
    if (e >= E) return;
    int d = dst[e];
    int p = row_ptr[d] + atomicAdd(&fillcnt[d], 1);
    col[p] = src[e];
}

// ---------------- layer-1 aggregation: aggA[n][b][64] = sum norm * x[b][s][64] ----------------
// block = one dst node; wave = batch; lane = channel. Source x is 20 MB (L2/L3-resident).
__global__ __launch_bounds__(256) void k_agg1(const float* __restrict__ x,
                                              const int* __restrict__ rp, const int* __restrict__ col,
                                              const float* __restrict__ dis,
                                              float* __restrict__ aggA, int N) {
    int n = blockIdx.x;
    int b = threadIdx.x >> 6, l = threadIdx.x & 63;
    const float* xb = x + (size_t)b * N * INDIM;
    float dn = dis[n];
    int beg = rp[n], end = rp[n + 1];
    float acc = xb[(size_t)n * INDIM + l] * (dn * dn);  // self-loop
    int e = beg;
    for (; e + 1 < end; e += 2) {
        int s0 = col[e], s1 = col[e + 1];
        float w0 = dis[s0] * dn, w1 = dis[s1] * dn;
        float v0 = xb[(size_t)s0 * INDIM + l];
        float v1 = xb[(size_t)s1 * INDIM + l];
        acc = fmaf(v0, w0, acc);
        acc = fmaf(v1, w1, acc);
    }
    if (e < end) {
        int s = col[e];
        acc = fmaf(xb[(size_t)s * INDIM + l], dis[s] * dn, acc);
    }
    aggA[((size_t)n * 4 + b) * INDIM + l] = acc;
}

// ---------------- GEMM1: x1 = relu(aggA @ W1 + b1), bf16 out, rows [n*4+b] ----------------
__global__ __launch_bounds__(256) void k_gemm1(const float* __restrict__ A, const float* __restrict__ W1,
                                               const float* __restrict__ b1, ushort* __restrict__ x1,
                                               int ntiles) {
    __shared__ float sW[INDIM][HID];   // 32 KB, staged once per block
    __shared__ float sX[16][INDIM];    // 4 KB
    int t = threadIdx.x, c = t & 63, w = t >> 6;
    for (int i = t; i < INDIM * HID; i += 256) sW[i >> 7][i & 127] = W1[i];
    float bc0 = b1[c], bc1 = b1[c + 64];
    for (int tile = blockIdx.x; tile < ntiles; tile += gridDim.x) {
        size_t rbase = (size_t)tile * 16;
        __syncthreads();
        for (int i = t; i < 16 * INDIM; i += 256) sX[i >> 6][i & 63] = A[rbase * INDIM + i];
        __syncthreads();
        float acc[4][2] = {};
#pragma unroll
        for (int k = 0; k < INDIM; k += 4) {
            float w0[4], w1[4];
#pragma unroll
            for (int kk = 0; kk < 4; kk++) { w0[kk] = sW[k + kk][c]; w1[kk] = sW[k + kk][c + 64]; }
#pragma unroll
            for (int i = 0; i < 4; i++) {
                float4 xv = *(const float4*)&sX[w + 4 * i][k];
                acc[i][0] = fmaf(xv.x, w0[0], acc[i][0]); acc[i][1] = fmaf(xv.x, w1[0], acc[i][1]);
                acc[i][0] = fmaf(xv.y, w0[1], acc[i][0]); acc[i][1] = fmaf(xv.y, w1[1], acc[i][1]);
                acc[i][0] = fmaf(xv.z, w0[2], acc[i][0]); acc[i][1] = fmaf(xv.z, w1[2], acc[i][1]);
                acc[i][0] = fmaf(xv.w, w0[3], acc[i][0]); acc[i][1] = fmaf(xv.w, w1[3], acc[i][1]);
            }
        }
#pragma unroll
        for (int i = 0; i < 4; i++) {
            size_t r = rbase + w + 4 * i;
            x1[r * HID + c]      = f2bf(fmaxf(acc[i][0] + bc0, 0.f));
            x1[r * HID + c + 64] = f2bf(fmaxf(acc[i][1] + bc1, 0.f));
        }
    }
}

// ---------------- layer-2 aggregation on bf16: aggB = sum norm * x1[s], bf16 in/out ----------------
// x1 rows are 64 dwords (128 bf16); lane = dword (2 channels). Source 20.5 MB.
__global__ __launch_bounds__(256) void k_agg2(const uint* __restrict__ x1,
                                              const int* __restrict__ rp, const int* __restrict__ col,
                                              const float* __restrict__ dis,
                                              uint* __restrict__ aggB, int N) {
    int n = blockIdx.x;
    int b = threadIdx.x >> 6, l = threadIdx.x & 63;
    float dn = dis[n];
    int beg = rp[n], end = rp[n + 1];
    uint v = x1[((size_t)n * 4 + b) * 64 + l];
    float sl = dn * dn;
    float a0 = bf2f(v & 0xffffu) * sl, a1 = bf2f(v >> 16) * sl;
    int e = beg;
    for (; e + 1 < end; e += 2) {
        int s0 = col[e], s1 = col[e + 1];
        float w0 = dis[s0] * dn, w1 = dis[s1] * dn;
        uint u0 = x1[((size_t)s0 * 4 + b) * 64 + l];
        uint u1 = x1[((size_t)s1 * 4 + b) * 64 + l];
        a0 = fmaf(bf2f(u0 & 0xffffu), w0, a0);
        a1 = fmaf(bf2f(u0 >> 16),     w0, a1);
        a0 = fmaf(bf2f(u1 & 0xffffu), w1, a0);
        a1 = fmaf(bf2f(u1 >> 16),     w1, a1);
    }
    if (e < end) {
        int s = col[e];
        float wg = dis[s] * dn;
        uint u = x1[((size_t)s * 4 + b) * 64 + l];
        a0 = fmaf(bf2f(u & 0xffffu), wg, a0);
        a1 = fmaf(bf2f(u >> 16),     wg, a1);
    }
    aggB[((size_t)n * 4 + b) * 64 + l] = (uint)f2bf(a0) | ((uint)f2bf(a1) << 16);
}

// ---------------- GEMM2 + bias + ReLU + mean-pool: pooled[b][c] += relu(aggB@W2+b2)/N ----------------
__global__ __launch_bounds__(256) void k_gemm2_pool(const uint* __restrict__ Abf,
                                                    const float* __restrict__ W2, const float* __restrict__ b2,
                                                    float* __restrict__ pooledS, int ntiles, float invN) {
    __shared__ float sW[HID][HID];     // 64 KB, staged once per block
    __shared__ float sX[16][HID];      // 8 KB
    int t = threadIdx.x, c = t & 63, w = t >> 6;
    for (int i = t; i < HID * HID; i += 256) sW[i >> 7][i & 127] = W2[i];
    float bc0 = b2[c], bc1 = b2[c + 64];
    float p0 = 0.f, p1 = 0.f;
    for (int tile = blockIdx.x; tile < ntiles; tile += gridDim.x) {
        size_t rbase = (size_t)tile * 16;
        __syncthreads();
        for (int i = t; i < 16 * 64; i += 256) {
            uint v = Abf[rbase * 64 + i];
            int rr = i >> 6, dd = i & 63;
            sX[rr][2 * dd]     = bf2f(v & 0xffffu);
            sX[rr][2 * dd + 1] = bf2f(v >> 16);
        }
        __syncthreads();
        float acc[4][2] = {};
#pragma unroll
        for (int k = 0; k < HID; k += 4) {
            float w0[4], w1[4];
#pragma unroll
            for (int kk = 0; kk < 4; kk++) { w0[kk] = sW[k + kk][c]; w1[kk] = sW[k + kk][c + 64]; }
#pragma unroll
            for (int i = 0; i < 4; i++) {
                float4 xv = *(const float4*)&sX[w + 4 * i][k];
                acc[i][0] = fmaf(xv.x, w0[0], acc[i][0]); acc[i][1] = fmaf(xv.x, w1[0], acc[i][1]);
                acc[i][0] = fmaf(xv.y, w0[1], acc[i][0]); acc[i][1] = fmaf(xv.y, w1[1], acc[i][1]);
                acc[i][0] = fmaf(xv.z, w0[2], acc[i][0]); acc[i][1] = fmaf(xv.z, w1[2], acc[i][1]);
                acc[i][0] = fmaf(xv.w, w0[3], acc[i][0]); acc[i][1] = fmaf(xv.w, w1[3], acc[i][1]);
            }
        }
        // rows rbase+w+4i: batch = (w+4i)&3 = w (rbase multiple of 16)
#pragma unroll
        for (int i = 0; i < 4; i++) {
            p0 += fmaxf(acc[i][0] + bc0, 0.f);
            p1 += fmaxf(acc[i][1] + bc1, 0.f);
        }
    }
    int sh = blockIdx.x & (NSH - 1);
    atomicAdd(&pooledS[sh * 512 + w * HID + c],      p0 * invN);
    atomicAdd(&pooledS[sh * 512 + w * HID + c + 64], p1 * invN);
}

// ---------------- head ----------------
__global__ __launch_bounds__(64) void k_head(const float* __restrict__ pooledS, const float* __restrict__ af,
                                             const float* __restrict__ fcw, const float* __restrict__ fcb,
                                             const float* __restrict__ sig, float* __restrict__ out, int B) {
    int t = threadIdx.x;
    if (t >= B * 16) return;
    int b = t >> 4, o = t & 15;
    float acc = fcb[o];
    for (int c = 0; c < HID; c++) {
        float pc = 0.f;
        for (int s = 0; s < NSH; s++) pc += pooledS[s * 512 + b * HID + c];
        acc = fmaf(pc, fcw[c * 16 + o], acc);
    }
    acc = fmaf(af[b], fcw[HID * 16 + o], acc);
    out[b * 16 + o] = acc;
    out[B * 16 + b * 16 + o] = expf(sig[o]);
}

// ---------------- launch ----------------

extern "C" void kernel_launch(void* const* d_in, const int* in_sizes, int n_in,
                              void* d_out, int out_size, void* d_ws, size_t ws_size,
                              hipStream_t stream) {
    const float* x   = (const float*)d_in[0];
    const float* af  = (const float*)d_in[1];
    const int*   ei  = (const int*)d_in[2];
    const float* W1  = (const float*)d_in[3];
    const float* b1  = (const float*)d_in[4];
    const float* W2  = (const float*)d_in[5];
    const float* b2  = (const float*)d_in[6];
    const float* fcw = (const float*)d_in[7];
    const float* fcb = (const float*)d_in[8];
    const float* sig = (const float*)d_in[9];

    int B = in_sizes[1];                 // 4
    int E = in_sizes[2] / 2;             // 320000
    int N = in_sizes[0] / (B * INDIM);   // 20000
    int nrows = B * N;                   // 80000
    int ntiles = nrows / 16;             // 5000

    char* p = (char*)d_ws;
    auto alloc = [&](size_t bytes) { void* r = (void*)p; p += (bytes + 255) & ~(size_t)255; return r; };
    int*    cnt     = (int*)alloc((size_t)N * 4);
    int*    fillcnt = (int*)alloc((size_t)N * 4);
    int*    row_ptr = (int*)alloc((size_t)(N + 1) * 4);
    int*    colA    = (int*)alloc((size_t)E * 4);
    int*    srcA    = (int*)alloc((size_t)E * 4);
    int*    dstA    = (int*)alloc((size_t)E * 4);
    float*  dis     = (float*)alloc((size_t)N * 4);
    float*  pooledS = (float*)alloc((size_t)NSH * 512 * 4);
    int*    flag    = (int*)alloc(256);
    float*  aggA    = (float*)alloc((size_t)nrows * INDIM * 4);   // 20.5 MB
    ushort* x1      = (ushort*)alloc((size_t)nrows * HID * 2);    // 20.5 MB bf16
    uint*   aggB    = (uint*)alloc((size_t)nrows * 64 * 4);       // 20.5 MB bf16 pairs
    (void)ws_size;

    int gN = (N + 255) / 256;
    int gE = (E + 255) / 256;

    k_init<<<gN, 256, 0, stream>>>(cnt, pooledS, flag, N, NSH * 512);
    k_detect<<<1, 256, 0, stream>>>(ei, flag);
    k_norm_edges<<<gE, 256, 0, stream>>>(ei, flag, srcA, dstA, E);
    k_count<<<gE, 256, 0, stream>>>(dstA, cnt, E);
    k_scan<<<1, 256, 0, stream>>>(cnt, row_ptr, dis, fillcnt, N);
    k_fill<<<gE, 256, 0, stream>>>(srcA, dstA, row_ptr, fillcnt, colA, E);

    k_agg1<<<N, 64 * B, 0, stream>>>(x, row_ptr, colA, dis, aggA, N);
    k_gemm1<<<1024, 256, 0, stream>>>(aggA, W1, b1, x1, ntiles);
    k_agg2<<<N, 64 * B, 0, stream>>>((const uint*)x1, row_ptr, colA, dis, aggB, N);
    k_gemm2_pool<<<512, 256, 0, stream>>>(aggB, W2, b2, pooledS, ntiles, 1.0f / (float)N);

    k_head<<<1, 64, 0, stream>>>(pooledS, af, fcw, fcb, sig, (float*)d_out, B);
}

// Round 3
// 248.466 us; speedup vs baseline: 2.0164x; 1.2834x over previous
//
#include <hip/hip_runtime.h>
#include <math.h>

#define HID 128
#define INDIM 64
#define NSH 32   // pooled shadow copies

typedef unsigned int uint;
typedef unsigned short ushort;
typedef __attribute__((ext_vector_type(8))) short short8;
typedef __attribute__((ext_vector_type(4))) float f32x4;

static __device__ inline float bf2f(uint h) { return __uint_as_float(h << 16); }
static __device__ inline ushort f2bf(float f) {
    uint u = __float_as_uint(f);
    return (ushort)((u + 0x7fff + ((u >> 16) & 1)) >> 16);  // RNE
}
static __device__ inline uint packbf2(float a, float b) {
    return (uint)f2bf(a) | ((uint)f2bf(b) << 16);
}

// ---------------- init + casts: xbf [n][b][64c] bf16, W1T/W2T [c][k] bf16 ----------------
__global__ __launch_bounds__(256) void k_init_cast(
    const float* __restrict__ x, const float* __restrict__ W1, const float* __restrict__ W2,
    uint* __restrict__ xbf, uint* __restrict__ w1t, uint* __restrict__ w2t,
    int* cnt, float* pooledS, int* flag, int N)
{
    int gid = blockIdx.x * 256 + threadIdx.x;
    int stride = gridDim.x * 256;
    int total = N * 128;  // bf16-pairs of xbf
    for (int i = gid; i < total; i += stride) {
        int n = i >> 7, r = i & 127;
        int b = r >> 5, c2 = r & 31;
        const float* s = x + ((size_t)b * N + n) * 64 + c2 * 2;
        xbf[i] = packbf2(s[0], s[1]);
    }
    if (gid < 128 * 32) { int c = gid >> 5, k2 = gid & 31; w1t[gid] = packbf2(W1[(2 * k2) * 128 + c], W1[(2 * k2 + 1) * 128 + c]); }
    if (gid < 128 * 64) { int c = gid >> 6, k2 = gid & 63; w2t[gid] = packbf2(W2[(2 * k2) * 128 + c], W2[(2 * k2 + 1) * 128 + c]); }
    if (gid < N) cnt[gid] = 0;
    if (gid < NSH * 512) pooledS[gid] = 0.f;
    if (gid == 0) *flag = 0;
}

// int32 vs int64 edge_index detection (int64 LE: high words of small values are 0)
__global__ __launch_bounds__(256) void k_detect(const int* ei, int* flag) {
    int t = threadIdx.x;
    if (ei[2 * t + 1] != 0) atomicOr(flag, 1);
}

// extract src/dst + degree count (fused)
__global__ __launch_bounds__(256) void k_edges(const int* __restrict__ ei, const int* __restrict__ flag,
                                               int* __restrict__ src, int* __restrict__ dst,
                                               int* cnt, int E) {
    int e = blockIdx.x * 256 + threadIdx.x;
    if (e >= E) return;
    int s, d;
    if (*flag) { s = ei[e]; d = ei[(size_t)E + e]; }
    else       { s = ei[2 * (size_t)e]; d = ei[2 * (size_t)E + 2 * (size_t)e]; }
    src[e] = s; dst[e] = d;
    atomicAdd(&cnt[d], 1);
}

__global__ __launch_bounds__(256) void k_scan(const int* __restrict__ cnt, int* row_ptr,
                                              float* dis, int* fillcnt, int N) {
    __shared__ int part[256];
    __shared__ int spart[256];
    int t = threadIdx.x;
    int chunk = (N + 255) >> 8;
    int lo = t * chunk; if (lo > N) lo = N;
    int hi = lo + chunk; if (hi > N) hi = N;
    int s = 0;
    for (int i = lo; i < hi; i++) s += cnt[i];
    part[t] = s;
    __syncthreads();
    if (t == 0) {
        int acc = 0;
        for (int i = 0; i < 256; i++) { spart[i] = acc; acc += part[i]; }
        row_ptr[N] = acc;
    }
    __syncthreads();
    int acc = spart[t];
    for (int i = lo; i < hi; i++) {
        row_ptr[i] = acc;
        acc += cnt[i];
        dis[i] = rsqrtf((float)(cnt[i] + 1));
        fillcnt[i] = 0;
    }
}

// CSR fill; also precompute wsrc[p] = dis[src] (removes dependent load from gather chain)
__global__ __launch_bounds__(256) void k_fill(const int* __restrict__ src, const int* __restrict__ dst,
                                              const int* __restrict__ row_ptr, int* fillcnt,
                                              int* __restrict__ col, float* __restrict__ wsrc,
                                              const float* __restrict__ dis, int E) {
    int e = blockIdx.x * 256 + threadIdx.x;
    if (e >= E) return;
    int d = dst[e], s = src[e];
    int p = row_ptr[d] + atomicAdd(&fillcnt[d], 1);
    col[p] = s;
    wsrc[p] = dis[s];
}

// ---------------- layer 1 fused: agg(xbf) -> LDS(swz) -> MFMA(W1T) -> relu -> x1 bf16 ----------------
// block = 4 waves; wave w aggregates node tile*4+w (rows [4b][64c] bf16 = 512B; lane: uint2, b=l>>4, chans 4*(l&15)..+3)
// MFMA swapped: A-op = W1T frag (chan x k), B-op = X frag (k x tilerow) => D[chan][tilerow]
__global__ __launch_bounds__(256) void k_l1(
    const uint* __restrict__ xbf, const int* __restrict__ rp, const int* __restrict__ col,
    const float* __restrict__ wsrc, const float* __restrict__ dis,
    const ushort* __restrict__ w1t, const float* __restrict__ b1,
    uint* __restrict__ x1, int ntile)
{
    __shared__ __align__(16) char sX[2048];   // 16 rows x 128B, XOR-swizzled
    int t = threadIdx.x, w = t >> 6, l = t & 63;
    int g = l >> 4, row = l & 15;
    int ct0 = 2 * w, ct1 = 2 * w + 1;
    // W frags: lane: chan_local = l&15, k = ks*32 + g*8 + j (16B contiguous from W1T[c][k])
    short8 wf00 = *(const short8*)(w1t + (ct0 * 16 + row) * 64 + g * 8);
    short8 wf01 = *(const short8*)(w1t + (ct0 * 16 + row) * 64 + 32 + g * 8);
    short8 wf10 = *(const short8*)(w1t + (ct1 * 16 + row) * 64 + g * 8);
    short8 wf11 = *(const short8*)(w1t + (ct1 * 16 + row) * 64 + 32 + g * 8);
    float4 bb0 = *(const float4*)(b1 + ct0 * 16 + g * 4);
    float4 bb1 = *(const float4*)(b1 + ct1 * 16 + g * 4);
    // LDS offsets: write 8B slot s8=l&15 of row wrow=w*4+g; read 16B slot ks*4+g of row l&15; both XOR row&7
    int wrow = w * 4 + g;
    int woff = wrow * 128 + ((((row) >> 1) ^ (wrow & 7)) << 4) + ((row & 1) << 3);
    int roff0 = row * 128 + (((0 + g) ^ (row & 7)) << 4);
    int roff1 = row * 128 + (((4 + g) ^ (row & 7)) << 4);
    const uint2* xr = (const uint2*)xbf;

    for (int tile = blockIdx.x; tile < ntile; tile += gridDim.x) {
        int n = tile * 4 + w;
        float dn = dis[n];
        int beg = rp[n], end = rp[n + 1];
        uint2 v = xr[(size_t)n * 64 + l];
        float sl = dn * dn;
        float a0 = bf2f(v.x & 0xffffu) * sl, a1 = bf2f(v.x >> 16) * sl;
        float a2 = bf2f(v.y & 0xffffu) * sl, a3 = bf2f(v.y >> 16) * sl;
        int e = beg;
        for (; e + 3 < end; e += 4) {
            int s0 = col[e], s1 = col[e + 1], s2 = col[e + 2], s3 = col[e + 3];
            float f0 = wsrc[e] * dn, f1 = wsrc[e + 1] * dn, f2 = wsrc[e + 2] * dn, f3 = wsrc[e + 3] * dn;
            uint2 u0 = xr[(size_t)s0 * 64 + l], u1 = xr[(size_t)s1 * 64 + l];
            uint2 u2 = xr[(size_t)s2 * 64 + l], u3 = xr[(size_t)s3 * 64 + l];
            a0 = fmaf(bf2f(u0.x & 0xffffu), f0, a0); a1 = fmaf(bf2f(u0.x >> 16), f0, a1);
            a2 = fmaf(bf2f(u0.y & 0xffffu), f0, a2); a3 = fmaf(bf2f(u0.y >> 16), f0, a3);
            a0 = fmaf(bf2f(u1.x & 0xffffu), f1, a0); a1 = fmaf(bf2f(u1.x >> 16), f1, a1);
            a2 = fmaf(bf2f(u1.y & 0xffffu), f1, a2); a3 = fmaf(bf2f(u1.y >> 16), f1, a3);
            a0 = fmaf(bf2f(u2.x & 0xffffu), f2, a0); a1 = fmaf(bf2f(u2.x >> 16), f2, a1);
            a2 = fmaf(bf2f(u2.y & 0xffffu), f2, a2); a3 = fmaf(bf2f(u2.y >> 16), f2, a3);
            a0 = fmaf(bf2f(u3.x & 0xffffu), f3, a0); a1 = fmaf(bf2f(u3.x >> 16), f3, a1);
            a2 = fmaf(bf2f(u3.y & 0xffffu), f3, a2); a3 = fmaf(bf2f(u3.y >> 16), f3, a3);
        }
        for (; e < end; e++) {
            int s = col[e];
            float f = wsrc[e] * dn;
            uint2 u = xr[(size_t)s * 64 + l];
            a0 = fmaf(bf2f(u.x & 0xffffu), f, a0); a1 = fmaf(bf2f(u.x >> 16), f, a1);
            a2 = fmaf(bf2f(u.y & 0xffffu), f, a2); a3 = fmaf(bf2f(u.y >> 16), f, a3);
        }
        __syncthreads();  // protect previous iteration's LDS reads
        uint2 pk; pk.x = packbf2(a0, a1); pk.y = packbf2(a2, a3);
        *(uint2*)(sX + woff) = pk;
        __syncthreads();
        short8 xf0 = *(const short8*)(sX + roff0);
        short8 xf1 = *(const short8*)(sX + roff1);
        f32x4 acc0 = {0.f, 0.f, 0.f, 0.f}, acc1 = {0.f, 0.f, 0.f, 0.f};
        acc0 = __builtin_amdgcn_mfma_f32_16x16x32_bf16(wf00, xf0, acc0, 0, 0, 0);
        acc0 = __builtin_amdgcn_mfma_f32_16x16x32_bf16(wf01, xf1, acc0, 0, 0, 0);
        acc1 = __builtin_amdgcn_mfma_f32_16x16x32_bf16(wf10, xf0, acc1, 0, 0, 0);
        acc1 = __builtin_amdgcn_mfma_f32_16x16x32_bf16(wf11, xf1, acc1, 0, 0, 0);
        // lane holds rows(tile) = l&15 = row, chans ct*16 + g*4 + i
        size_t r = (size_t)tile * 16 + row;
        uint2 o0, o1;
        o0.x = packbf2(fmaxf(acc0.x + bb0.x, 0.f), fmaxf(acc0.y + bb0.y, 0.f));
        o0.y = packbf2(fmaxf(acc0.z + bb0.z, 0.f), fmaxf(acc0.w + bb0.w, 0.f));
        o1.x = packbf2(fmaxf(acc1.x + bb1.x, 0.f), fmaxf(acc1.y + bb1.y, 0.f));
        o1.y = packbf2(fmaxf(acc1.z + bb1.z, 0.f), fmaxf(acc1.w + bb1.w, 0.f));
        ((uint2*)x1)[r * 32 + ct0 * 4 + g] = o0;
        ((uint2*)x1)[r * 32 + ct1 * 4 + g] = o1;
    }
}

// ---------------- layer 2 fused: agg(x1) -> LDS(swz) -> MFMA(W2T) -> relu -> mean-pool ----------------
// wave aggregates node rows [4b][128c] bf16 = 1KB; lane: uint4, b=l>>4, chans 8*(l&15)..+7
__global__ __launch_bounds__(256) void k_l2(
    const uint* __restrict__ x1, const int* __restrict__ rp, const int* __restrict__ col,
    const float* __restrict__ wsrc, const float* __restrict__ dis,
    const ushort* __restrict__ w2t, const float* __restrict__ b2,
    float* __restrict__ pooledS, int ntile, float invN)
{
    __shared__ __align__(16) char sX[4096];   // 16 rows x 256B, XOR-swizzled
    int t = threadIdx.x, w = t >> 6, l = t & 63;
    int g = l >> 4, row = l & 15;
    int ct0 = 2 * w, ct1 = 2 * w + 1;
    short8 wf0[4], wf1[4];
#pragma unroll
    for (int ks = 0; ks < 4; ks++) {
        wf0[ks] = *(const short8*)(w2t + (ct0 * 16 + row) * 128 + ks * 32 + g * 8);
        wf1[ks] = *(const short8*)(w2t + (ct1 * 16 + row) * 128 + ks * 32 + g * 8);
    }
    float4 bb0 = *(const float4*)(b2 + ct0 * 16 + g * 4);
    float4 bb1 = *(const float4*)(b2 + ct1 * 16 + g * 4);
    int wrow = w * 4 + g;
    int woff = wrow * 256 + (((row) ^ (wrow & 7)) << 4);
    int roff[4];
#pragma unroll
    for (int ks = 0; ks < 4; ks++) roff[ks] = row * 256 + (((ks * 4 + g) ^ (row & 7)) << 4);
    const uint4* xr = (const uint4*)x1;
    float p0[4] = {0.f, 0.f, 0.f, 0.f}, p1[4] = {0.f, 0.f, 0.f, 0.f};

    for (int tile = blockIdx.x; tile < ntile; tile += gridDim.x) {
        int n = tile * 4 + w;
        float dn = dis[n];
        int beg = rp[n], end = rp[n + 1];
        uint4 v = xr[(size_t)n * 64 + l];
        float sl = dn * dn;
        float a0 = bf2f(v.x & 0xffffu) * sl, a1 = bf2f(v.x >> 16) * sl;
        float a2 = bf2f(v.y & 0xffffu) * sl, a3 = bf2f(v.y >> 16) * sl;
        float a4 = bf2f(v.z & 0xffffu) * sl, a5 = bf2f(v.z >> 16) * sl;
        float a6 = bf2f(v.w & 0xffffu) * sl, a7 = bf2f(v.w >> 16) * sl;
        int e = beg;
        for (; e + 1 < end; e += 2) {
            int s0 = col[e], s1 = col[e + 1];
            float f0 = wsrc[e] * dn, f1 = wsrc[e + 1] * dn;
            uint4 u0 = xr[(size_t)s0 * 64 + l], u1 = xr[(size_t)s1 * 64 + l];
            a0 = fmaf(bf2f(u0.x & 0xffffu), f0, a0); a1 = fmaf(bf2f(u0.x >> 16), f0, a1);
            a2 = fmaf(bf2f(u0.y & 0xffffu), f0, a2); a3 = fmaf(bf2f(u0.y >> 16), f0, a3);
            a4 = fmaf(bf2f(u0.z & 0xffffu), f0, a4); a5 = fmaf(bf2f(u0.z >> 16), f0, a5);
            a6 = fmaf(bf2f(u0.w & 0xffffu), f0, a6); a7 = fmaf(bf2f(u0.w >> 16), f0, a7);
            a0 = fmaf(bf2f(u1.x & 0xffffu), f1, a0); a1 = fmaf(bf2f(u1.x >> 16), f1, a1);
            a2 = fmaf(bf2f(u1.y & 0xffffu), f1, a2); a3 = fmaf(bf2f(u1.y >> 16), f1, a3);
            a4 = fmaf(bf2f(u1.z & 0xffffu), f1, a4); a5 = fmaf(bf2f(u1.z >> 16), f1, a5);
            a6 = fmaf(bf2f(u1.w & 0xffffu), f1, a6); a7 = fmaf(bf2f(u1.w >> 16), f1, a7);
        }
        if (e < end) {
            int s = col[e];
            float f = wsrc[e] * dn;
            uint4 u = xr[(size_t)s * 64 + l];
            a0 = fmaf(bf2f(u.x & 0xffffu), f, a0); a1 = fmaf(bf2f(u.x >> 16), f, a1);
            a2 = fmaf(bf2f(u.y & 0xffffu), f, a2); a3 = fmaf(bf2f(u.y >> 16), f, a3);
            a4 = fmaf(bf2f(u.z & 0xffffu), f, a4); a5 = fmaf(bf2f(u.z >> 16), f, a5);
            a6 = fmaf(bf2f(u.w & 0xffffu), f, a6); a7 = fmaf(bf2f(u.w >> 16), f, a7);
        }
        __syncthreads();
        uint4 pk;
        pk.x = packbf2(a0, a1); pk.y = packbf2(a2, a3);
        pk.z = packbf2(a4, a5); pk.w = packbf2(a6, a7);
        *(uint4*)(sX + woff) = pk;
        __syncthreads();
        short8 xf[4];
#pragma unroll
        for (int ks = 0; ks < 4; ks++) xf[ks] = *(const short8*)(sX + roff[ks]);
        f32x4 acc0 = {0.f, 0.f, 0.f, 0.f}, acc1 = {0.f, 0.f, 0.f, 0.f};
#pragma unroll
        for (int ks = 0; ks < 4; ks++) {
            acc0 = __builtin_amdgcn_mfma_f32_16x16x32_bf16(wf0[ks], xf[ks], acc0, 0, 0, 0);
            acc1 = __builtin_amdgcn_mfma_f32_16x16x32_bf16(wf1[ks], xf[ks], acc1, 0, 0, 0);
        }
        p0[0] += fmaxf(acc0.x + bb0.x, 0.f); p0[1] += fmaxf(acc0.y + bb0.y, 0.f);
        p0[2] += fmaxf(acc0.z + bb0.z, 0.f); p0[3] += fmaxf(acc0.w + bb0.w, 0.f);
        p1[0] += fmaxf(acc1.x + bb1.x, 0.f); p1[1] += fmaxf(acc1.y + bb1.y, 0.f);
        p1[2] += fmaxf(acc1.z + bb1.z, 0.f); p1[3] += fmaxf(acc1.w + bb1.w, 0.f);
    }
    // rows with same batch b = row&3 live in lanes l, l^4, l^8
#pragma unroll
    for (int i = 0; i < 4; i++) {
        p0[i] += __shfl_xor(p0[i], 4); p0[i] += __shfl_xor(p0[i], 8);
        p1[i] += __shfl_xor(p1[i], 4); p1[i] += __shfl_xor(p1[i], 8);
    }
    if ((l & 12) == 0) {
        int b = l & 3;
        float* pd = pooledS + (size_t)(blockIdx.x & (NSH - 1)) * 512 + b * 128;
#pragma unroll
        for (int i = 0; i < 4; i++) {
            atomicAdd(&pd[ct0 * 16 + g * 4 + i], p0[i] * invN);
            atomicAdd(&pd[ct1 * 16 + g * 4 + i], p1[i] * invN);
        }
    }
}

// ---------------- head ----------------
__global__ __launch_bounds__(64) void k_head(const float* __restrict__ pooledS, const float* __restrict__ af,
                                             const float* __restrict__ fcw, const float* __restrict__ fcb,
                                             const float* __restrict__ sig, float* __restrict__ out, int B) {
    int t = threadIdx.x;
    if (t >= B * 16) return;
    int b = t >> 4, o = t & 15;
    float acc = fcb[o];
    for (int c = 0; c < HID; c++) {
        float pc = 0.f;
        for (int s = 0; s < NSH; s++) pc += pooledS[s * 512 + b * 128 + c];
        acc = fmaf(pc, fcw[c * 16 + o], acc);
    }
    acc = fmaf(af[b], fcw[HID * 16 + o], acc);
    out[b * 16 + o] = acc;
    out[B * 16 + b * 16 + o] = expf(sig[o]);
}

// ---------------- launch ----------------

extern "C" void kernel_launch(void* const* d_in, const int* in_sizes, int n_in,
                              void* d_out, int out_size, void* d_ws, size_t ws_size,
                              hipStream_t stream) {
    const float* x   = (const float*)d_in[0];
    const float* af  = (const float*)d_in[1];
    const int*   ei  = (const int*)d_in[2];
    const float* W1  = (const float*)d_in[3];
    const float* b1  = (const float*)d_in[4];
    const float* W2  = (const float*)d_in[5];
    const float* b2  = (const float*)d_in[6];
    const float* fcw = (const float*)d_in[7];
    const float* fcb = (const float*)d_in[8];
    const float* sig = (const float*)d_in[9];

    int B = in_sizes[1];                 // 4
    int E = in_sizes[2] / 2;             // 320000
    int N = in_sizes[0] / (B * INDIM);   // 20000
    int ntile = N / 4;                   // 5000 (16-row MFMA tiles)

    char* p = (char*)d_ws;
    auto alloc = [&](size_t bytes) { void* r = (void*)p; p += (bytes + 255) & ~(size_t)255; return r; };
    int*    cnt     = (int*)alloc((size_t)N * 4);
    int*    fillcnt = (int*)alloc((size_t)N * 4);
    int*    row_ptr = (int*)alloc((size_t)(N + 1) * 4);
    int*    colA    = (int*)alloc((size_t)E * 4);
    int*    srcA    = (int*)alloc((size_t)E * 4);
    int*    dstA    = (int*)alloc((size_t)E * 4);
    float*  wsrcA   = (float*)alloc((size_t)E * 4);
    float*  dis     = (float*)alloc((size_t)N * 4);
    float*  pooledS = (float*)alloc((size_t)NSH * 512 * 4);
    int*    flag    = (int*)alloc(256);
    uint*   xbf     = (uint*)alloc((size_t)N * 128 * 4);      // 10.25 MB bf16 [n][b][64c]
    uint*   x1      = (uint*)alloc((size_t)N * 4 * 64 * 4);   // 20.5 MB bf16 [r][128c]
    uint*   w1t     = (uint*)alloc((size_t)128 * 32 * 4);     // bf16 [128c][64k]
    uint*   w2t     = (uint*)alloc((size_t)128 * 64 * 4);     // bf16 [128c][128k]
    (void)ws_size;

    int gE = (E + 255) / 256;

    k_init_cast<<<2048, 256, 0, stream>>>(x, W1, W2, xbf, w1t, w2t, cnt, pooledS, flag, N);
    k_detect<<<1, 256, 0, stream>>>(ei, flag);
    k_edges<<<gE, 256, 0, stream>>>(ei, flag, srcA, dstA, cnt, E);
    k_scan<<<1, 256, 0, stream>>>(cnt, row_ptr, dis, fillcnt, N);
    k_fill<<<gE, 256, 0, stream>>>(srcA, dstA, row_ptr, fillcnt, colA, wsrcA, dis, E);

    k_l1<<<2048, 256, 0, stream>>>(xbf, row_ptr, colA, wsrcA, dis, (const ushort*)w1t, b1, x1, ntile);
    k_l2<<<1024, 256, 0, stream>>>(x1, row_ptr, colA, wsrcA, dis, (const ushort*)w2t, b2, pooledS, ntile, 1.0f / (float)N);

    k_head<<<1, 64, 0, stream>>>(pooledS, af, fcw, fcb, sig, (float*)d_out, B);
}

// Round 4
// 246.089 us; speedup vs baseline: 2.0358x; 1.0097x over previous
//
#include <hip/hip_runtime.h>
#include <math.h>

#define HID 128
#define INDIM 64
#define NSH 32   // pooled shadow copies

typedef unsigned int uint;
typedef unsigned short ushort;
typedef __attribute__((ext_vector_type(8))) short short8;
typedef __attribute__((ext_vector_type(4))) float f32x4;

static __device__ inline float bf2f(uint h) { return __uint_as_float(h << 16); }
static __device__ inline ushort f2bf(float f) {
    uint u = __float_as_uint(f);
    return (ushort)((u + 0x7fff + ((u >> 16) & 1)) >> 16);  // RNE
}
static __device__ inline uint packbf2(float a, float b) {
    return (uint)f2bf(a) | ((uint)f2bf(b) << 16);
}

// ---------------- init + casts + int32/int64 detect ----------------
__global__ __launch_bounds__(256) void k_init_cast(
    const float* __restrict__ x, const float* __restrict__ W1, const float* __restrict__ W2,
    const int* __restrict__ ei,
    uint* __restrict__ xbf, uint* __restrict__ w1t, uint* __restrict__ w2t,
    int* cnt, float* pooledS, int* flag, int N)
{
    int gid = blockIdx.x * 256 + threadIdx.x;
    int stride = gridDim.x * 256;
    // block 0: detect layout (int64 LE: high words of first 256 entries are all 0)
    if (blockIdx.x == 0) {
        __shared__ int sbad;
        if (threadIdx.x == 0) sbad = 0;
        __syncthreads();
        int bad = (ei[2 * threadIdx.x + 1] != 0) ? 1 : 0;
        if (__any(bad) && (threadIdx.x & 63) == 0) atomicOr(&sbad, 1);
        __syncthreads();
        if (threadIdx.x == 0) *flag = sbad;
    }
    int total = N * 128;  // bf16-pairs of xbf
    for (int i = gid; i < total; i += stride) {
        int n = i >> 7, r = i & 127;
        int b = r >> 5, c2 = r & 31;
        const float* s = x + ((size_t)b * N + n) * 64 + c2 * 2;
        xbf[i] = packbf2(s[0], s[1]);
    }
    if (gid < 128 * 32) { int c = gid >> 5, k2 = gid & 31; w1t[gid] = packbf2(W1[(2 * k2) * 128 + c], W1[(2 * k2 + 1) * 128 + c]); }
    if (gid < 128 * 64) { int c = gid >> 6, k2 = gid & 63; w2t[gid] = packbf2(W2[(2 * k2) * 128 + c], W2[(2 * k2 + 1) * 128 + c]); }
    if (gid < N) cnt[gid] = 0;
    if (gid < NSH * 512) pooledS[gid] = 0.f;
}

// extract src/dst + degree count (fused)
__global__ __launch_bounds__(256) void k_edges(const int* __restrict__ ei, const int* __restrict__ flag,
                                               int* __restrict__ src, int* __restrict__ dst,
                                               int* cnt, int E) {
    int e = blockIdx.x * 256 + threadIdx.x;
    if (e >= E) return;
    int s, d;
    if (*flag) { s = ei[e]; d = ei[(size_t)E + e]; }
    else       { s = ei[2 * (size_t)e]; d = ei[2 * (size_t)E + 2 * (size_t)e]; }
    src[e] = s; dst[e] = d;
    atomicAdd(&cnt[d], 1);
}

__global__ __launch_bounds__(256) void k_scan(const int* __restrict__ cnt, int* row_ptr,
                                              float* dis, int* fillcnt, int N) {
    __shared__ int part[256];
    __shared__ int spart[256];
    int t = threadIdx.x;
    int chunk = (N + 255) >> 8;
    int lo = t * chunk; if (lo > N) lo = N;
    int hi = lo + chunk; if (hi > N) hi = N;
    int s = 0;
    for (int i = lo; i < hi; i++) s += cnt[i];
    part[t] = s;
    __syncthreads();
    if (t == 0) {
        int acc = 0;
        for (int i = 0; i < 256; i++) { spart[i] = acc; acc += part[i]; }
        row_ptr[N] = acc;
    }
    __syncthreads();
    int acc = spart[t];
    for (int i = lo; i < hi; i++) {
        row_ptr[i] = acc;
        acc += cnt[i];
        dis[i] = rsqrtf((float)(cnt[i] + 1));
        fillcnt[i] = 0;
    }
}

// CSR fill; wsrc[p] = dis[src] precomputed (removes dependent load from gather chain)
__global__ __launch_bounds__(256) void k_fill(const int* __restrict__ src, const int* __restrict__ dst,
                                              const int* __restrict__ row_ptr, int* fillcnt,
                                              int* __restrict__ col, float* __restrict__ wsrc,
                                              const float* __restrict__ dis, int E) {
    int e = blockIdx.x * 256 + threadIdx.x;
    if (e >= E) return;
    int d = dst[e], s = src[e];
    int p = row_ptr[d] + atomicAdd(&fillcnt[d], 1);
    col[p] = s;
    wsrc[p] = dis[s];
}

// ---------------- layer 1 fused: agg(xbf) -> LDS(swz,dbuf) -> MFMA(W1T) -> relu -> x1 bf16 ----------------
__global__ __launch_bounds__(256) void k_l1(
    const uint* __restrict__ xbf, const int* __restrict__ rp, const int* __restrict__ col,
    const float* __restrict__ wsrc, const float* __restrict__ dis,
    const ushort* __restrict__ w1t, const float* __restrict__ b1,
    uint* __restrict__ x1, int ntile)
{
    __shared__ __align__(16) char sX[2 * 2048];   // dbuf: 2 x (16 rows x 128B), XOR-swizzled
    int t = threadIdx.x, w = t >> 6, l = t & 63;
    int g = l >> 4, row = l & 15;
    int ct0 = 2 * w, ct1 = 2 * w + 1;
    short8 wf00 = *(const short8*)(w1t + (ct0 * 16 + row) * 64 + g * 8);
    short8 wf01 = *(const short8*)(w1t + (ct0 * 16 + row) * 64 + 32 + g * 8);
    short8 wf10 = *(const short8*)(w1t + (ct1 * 16 + row) * 64 + g * 8);
    short8 wf11 = *(const short8*)(w1t + (ct1 * 16 + row) * 64 + 32 + g * 8);
    float4 bb0 = *(const float4*)(b1 + ct0 * 16 + g * 4);
    float4 bb1 = *(const float4*)(b1 + ct1 * 16 + g * 4);
    int wrow = w * 4 + g;
    int woff = wrow * 128 + ((((row) >> 1) ^ (wrow & 7)) << 4) + ((row & 1) << 3);
    int roff0 = row * 128 + (((0 + g) ^ (row & 7)) << 4);
    int roff1 = row * 128 + (((4 + g) ^ (row & 7)) << 4);
    const uint2* xr = (const uint2*)xbf;

    int it = 0;
    for (int tile = blockIdx.x; tile < ntile; tile += gridDim.x, it++) {
        int n = tile * 4 + w;
        float dn = dis[n];
        int beg = rp[n], end = rp[n + 1];
        uint2 v = xr[(size_t)n * 64 + l];
        float sl = dn * dn;
        float a0 = bf2f(v.x & 0xffffu) * sl, a1 = bf2f(v.x >> 16) * sl;
        float a2 = bf2f(v.y & 0xffffu) * sl, a3 = bf2f(v.y >> 16) * sl;
        int e = beg;
        for (; e + 3 < end; e += 4) {
            int s0 = col[e], s1 = col[e + 1], s2 = col[e + 2], s3 = col[e + 3];
            float f0 = wsrc[e] * dn, f1 = wsrc[e + 1] * dn, f2 = wsrc[e + 2] * dn, f3 = wsrc[e + 3] * dn;
            uint2 u0 = xr[(size_t)s0 * 64 + l], u1 = xr[(size_t)s1 * 64 + l];
            uint2 u2 = xr[(size_t)s2 * 64 + l], u3 = xr[(size_t)s3 * 64 + l];
            a0 = fmaf(bf2f(u0.x & 0xffffu), f0, a0); a1 = fmaf(bf2f(u0.x >> 16), f0, a1);
            a2 = fmaf(bf2f(u0.y & 0xffffu), f0, a2); a3 = fmaf(bf2f(u0.y >> 16), f0, a3);
            a0 = fmaf(bf2f(u1.x & 0xffffu), f1, a0); a1 = fmaf(bf2f(u1.x >> 16), f1, a1);
            a2 = fmaf(bf2f(u1.y & 0xffffu), f1, a2); a3 = fmaf(bf2f(u1.y >> 16), f1, a3);
            a0 = fmaf(bf2f(u2.x & 0xffffu), f2, a0); a1 = fmaf(bf2f(u2.x >> 16), f2, a1);
            a2 = fmaf(bf2f(u2.y & 0xffffu), f2, a2); a3 = fmaf(bf2f(u2.y >> 16), f2, a3);
            a0 = fmaf(bf2f(u3.x & 0xffffu), f3, a0); a1 = fmaf(bf2f(u3.x >> 16), f3, a1);
            a2 = fmaf(bf2f(u3.y & 0xffffu), f3, a2); a3 = fmaf(bf2f(u3.y >> 16), f3, a3);
        }
        for (; e < end; e++) {
            int s = col[e];
            float f = wsrc[e] * dn;
            uint2 u = xr[(size_t)s * 64 + l];
            a0 = fmaf(bf2f(u.x & 0xffffu), f, a0); a1 = fmaf(bf2f(u.x >> 16), f, a1);
            a2 = fmaf(bf2f(u.y & 0xffffu), f, a2); a3 = fmaf(bf2f(u.y >> 16), f, a3);
        }
        char* wb = sX + (it & 1) * 2048;
        uint2 pk; pk.x = packbf2(a0, a1); pk.y = packbf2(a2, a3);
        *(uint2*)(wb + woff) = pk;
        __syncthreads();
        short8 xf0 = *(const short8*)(wb + roff0);
        short8 xf1 = *(const short8*)(wb + roff1);
        f32x4 acc0 = {0.f, 0.f, 0.f, 0.f}, acc1 = {0.f, 0.f, 0.f, 0.f};
        acc0 = __builtin_amdgcn_mfma_f32_16x16x32_bf16(wf00, xf0, acc0, 0, 0, 0);
        acc0 = __builtin_amdgcn_mfma_f32_16x16x32_bf16(wf01, xf1, acc0, 0, 0, 0);
        acc1 = __builtin_amdgcn_mfma_f32_16x16x32_bf16(wf10, xf0, acc1, 0, 0, 0);
        acc1 = __builtin_amdgcn_mfma_f32_16x16x32_bf16(wf11, xf1, acc1, 0, 0, 0);
        size_t r = (size_t)tile * 16 + row;
        uint2 o0, o1;
        o0.x = packbf2(fmaxf(acc0.x + bb0.x, 0.f), fmaxf(acc0.y + bb0.y, 0.f));
        o0.y = packbf2(fmaxf(acc0.z + bb0.z, 0.f), fmaxf(acc0.w + bb0.w, 0.f));
        o1.x = packbf2(fmaxf(acc1.x + bb1.x, 0.f), fmaxf(acc1.y + bb1.y, 0.f));
        o1.y = packbf2(fmaxf(acc1.z + bb1.z, 0.f), fmaxf(acc1.w + bb1.w, 0.f));
        ((uint2*)x1)[r * 32 + ct0 * 4 + g] = o0;
        ((uint2*)x1)[r * 32 + ct1 * 4 + g] = o1;
    }
}

// ---------------- layer 2 fused: agg(x1) -> LDS(swz,dbuf) -> MFMA(W2T) -> relu -> mean-pool ----------------
__global__ __launch_bounds__(256) void k_l2(
    const uint* __restrict__ x1, const int* __restrict__ rp, const int* __restrict__ col,
    const float* __restrict__ wsrc, const float* __restrict__ dis,
    const ushort* __restrict__ w2t, const float* __restrict__ b2,
    float* __restrict__ pooledS, int ntile, float invN)
{
    __shared__ __align__(16) char sX[2 * 4096];   // dbuf: 2 x (16 rows x 256B), XOR-swizzled
    int t = threadIdx.x, w = t >> 6, l = t & 63;
    int g = l >> 4, row = l & 15;
    int ct0 = 2 * w, ct1 = 2 * w + 1;
    short8 wf0[4], wf1[4];
#pragma unroll
    for (int ks = 0; ks < 4; ks++) {
        wf0[ks] = *(const short8*)(w2t + (ct0 * 16 + row) * 128 + ks * 32 + g * 8);
        wf1[ks] = *(const short8*)(w2t + (ct1 * 16 + row) * 128 + ks * 32 + g * 8);
    }
    float4 bb0 = *(const float4*)(b2 + ct0 * 16 + g * 4);
    float4 bb1 = *(const float4*)(b2 + ct1 * 16 + g * 4);
    int wrow = w * 4 + g;
    int woff = wrow * 256 + (((row) ^ (wrow & 7)) << 4);
    int roff[4];
#pragma unroll
    for (int ks = 0; ks < 4; ks++) roff[ks] = row * 256 + (((ks * 4 + g) ^ (row & 7)) << 4);
    const uint4* xr = (const uint4*)x1;
    float p0[4] = {0.f, 0.f, 0.f, 0.f}, p1[4] = {0.f, 0.f, 0.f, 0.f};

    int it = 0;
    for (int tile = blockIdx.x; tile < ntile; tile += gridDim.x, it++) {
        int n = tile * 4 + w;
        float dn = dis[n];
        int beg = rp[n], end = rp[n + 1];
        uint4 v = xr[(size_t)n * 64 + l];
        float sl = dn * dn;
        float a0 = bf2f(v.x & 0xffffu) * sl, a1 = bf2f(v.x >> 16) * sl;
        float a2 = bf2f(v.y & 0xffffu) * sl, a3 = bf2f(v.y >> 16) * sl;
        float a4 = bf2f(v.z & 0xffffu) * sl, a5 = bf2f(v.z >> 16) * sl;
        float a6 = bf2f(v.w & 0xffffu) * sl, a7 = bf2f(v.w >> 16) * sl;
        int e = beg;
        for (; e + 3 < end; e += 4) {
            int s0 = col[e], s1 = col[e + 1], s2 = col[e + 2], s3 = col[e + 3];
            float f0 = wsrc[e] * dn, f1 = wsrc[e + 1] * dn;
            float f2 = wsrc[e + 2] * dn, f3 = wsrc[e + 3] * dn;
            uint4 u0 = xr[(size_t)s0 * 64 + l], u1 = xr[(size_t)s1 * 64 + l];
            uint4 u2 = xr[(size_t)s2 * 64 + l], u3 = xr[(size_t)s3 * 64 + l];
            a0 = fmaf(bf2f(u0.x & 0xffffu), f0, a0); a1 = fmaf(bf2f(u0.x >> 16), f0, a1);
            a2 = fmaf(bf2f(u0.y & 0xffffu), f0, a2); a3 = fmaf(bf2f(u0.y >> 16), f0, a3);
            a4 = fmaf(bf2f(u0.z & 0xffffu), f0, a4); a5 = fmaf(bf2f(u0.z >> 16), f0, a5);
            a6 = fmaf(bf2f(u0.w & 0xffffu), f0, a6); a7 = fmaf(bf2f(u0.w >> 16), f0, a7);
            a0 = fmaf(bf2f(u1.x & 0xffffu), f1, a0); a1 = fmaf(bf2f(u1.x >> 16), f1, a1);
            a2 = fmaf(bf2f(u1.y & 0xffffu), f1, a2); a3 = fmaf(bf2f(u1.y >> 16), f1, a3);
            a4 = fmaf(bf2f(u1.z & 0xffffu), f1, a4); a5 = fmaf(bf2f(u1.z >> 16), f1, a5);
            a6 = fmaf(bf2f(u1.w & 0xffffu), f1, a6); a7 = fmaf(bf2f(u1.w >> 16), f1, a7);
            a0 = fmaf(bf2f(u2.x & 0xffffu), f2, a0); a1 = fmaf(bf2f(u2.x >> 16), f2, a1);
            a2 = fmaf(bf2f(u2.y & 0xffffu), f2, a2); a3 = fmaf(bf2f(u2.y >> 16), f2, a3);
            a4 = fmaf(bf2f(u2.z & 0xffffu), f2, a4); a5 = fmaf(bf2f(u2.z >> 16), f2, a5);
            a6 = fmaf(bf2f(u2.w & 0xffffu), f2, a6); a7 = fmaf(bf2f(u2.w >> 16), f2, a7);
            a0 = fmaf(bf2f(u3.x & 0xffffu), f3, a0); a1 = fmaf(bf2f(u3.x >> 16), f3, a1);
            a2 = fmaf(bf2f(u3.y & 0xffffu), f3, a2); a3 = fmaf(bf2f(u3.y >> 16), f3, a3);
            a4 = fmaf(bf2f(u3.z & 0xffffu), f3, a4); a5 = fmaf(bf2f(u3.z >> 16), f3, a5);
            a6 = fmaf(bf2f(u3.w & 0xffffu), f3, a6); a7 = fmaf(bf2f(u3.w >> 16), f3, a7);
        }
        for (; e < end; e++) {
            int s = col[e];
            float f = wsrc[e] * dn;
            uint4 u = xr[(size_t)s * 64 + l];
            a0 = fmaf(bf2f(u.x & 0xffffu), f, a0); a1 = fmaf(bf2f(u.x >> 16), f, a1);
            a2 = fmaf(bf2f(u.y & 0xffffu), f, a2); a3 = fmaf(bf2f(u.y >> 16), f, a3);
            a4 = fmaf(bf2f(u.z & 0xffffu), f, a4); a5 = fmaf(bf2f(u.z >> 16), f, a5);
            a6 = fmaf(bf2f(u.w & 0xffffu), f, a6); a7 = fmaf(bf2f(u.w >> 16), f, a7);
        }
        char* wb = sX + (it & 1) * 4096;
        uint4 pk;
        pk.x = packbf2(a0, a1); pk.y = packbf2(a2, a3);
        pk.z = packbf2(a4, a5); pk.w = packbf2(a6, a7);
        *(uint4*)(wb + woff) = pk;
        __syncthreads();
        short8 xf[4];
#pragma unroll
        for (int ks = 0; ks < 4; ks++) xf[ks] = *(const short8*)(wb + roff[ks]);
        f32x4 acc0 = {0.f, 0.f, 0.f, 0.f}, acc1 = {0.f, 0.f, 0.f, 0.f};
#pragma unroll
        for (int ks = 0; ks < 4; ks++) {
            acc0 = __builtin_amdgcn_mfma_f32_16x16x32_bf16(wf0[ks], xf[ks], acc0, 0, 0, 0);
            acc1 = __builtin_amdgcn_mfma_f32_16x16x32_bf16(wf1[ks], xf[ks], acc1, 0, 0, 0);
        }
        p0[0] += fmaxf(acc0.x + bb0.x, 0.f); p0[1] += fmaxf(acc0.y + bb0.y, 0.f);
        p0[2] += fmaxf(acc0.z + bb0.z, 0.f); p0[3] += fmaxf(acc0.w + bb0.w, 0.f);
        p1[0] += fmaxf(acc1.x + bb1.x, 0.f); p1[1] += fmaxf(acc1.y + bb1.y, 0.f);
        p1[2] += fmaxf(acc1.z + bb1.z, 0.f); p1[3] += fmaxf(acc1.w + bb1.w, 0.f);
    }
    // rows with same batch b = row&3 live in lanes l, l^4, l^8
#pragma unroll
    for (int i = 0; i < 4; i++) {
        p0[i] += __shfl_xor(p0[i], 4); p0[i] += __shfl_xor(p0[i], 8);
        p1[i] += __shfl_xor(p1[i], 4); p1[i] += __shfl_xor(p1[i], 8);
    }
    if ((l & 12) == 0) {
        int b = l & 3;
        float* pd = pooledS + (size_t)(blockIdx.x & (NSH - 1)) * 512 + b * 128;
#pragma unroll
        for (int i = 0; i < 4; i++) {
            atomicAdd(&pd[ct0 * 16 + g * 4 + i], p0[i] * invN);
            atomicAdd(&pd[ct1 * 16 + g * 4 + i], p1[i] * invN);
        }
    }
}

// ---------------- head ----------------
__global__ __launch_bounds__(64) void k_head(const float* __restrict__ pooledS, const float* __restrict__ af,
                                             const float* __restrict__ fcw, const float* __restrict__ fcb,
                                             const float* __restrict__ sig, float* __restrict__ out, int B) {
    int t = threadIdx.x;
    if (t >= B * 16) return;
    int b = t >> 4, o = t & 15;
    float acc = fcb[o];
    for (int c = 0; c < HID; c++) {
        float pc = 0.f;
        for (int s = 0; s < NSH; s++) pc += pooledS[s * 512 + b * 128 + c];
        acc = fmaf(pc, fcw[c * 16 + o], acc);
    }
    acc = fmaf(af[b], fcw[HID * 16 + o], acc);
    out[b * 16 + o] = acc;
    out[B * 16 + b * 16 + o] = expf(sig[o]);
}

// ---------------- launch ----------------

extern "C" void kernel_launch(void* const* d_in, const int* in_sizes, int n_in,
                              void* d_out, int out_size, void* d_ws, size_t ws_size,
                              hipStream_t stream) {
    const float* x   = (const float*)d_in[0];
    const float* af  = (const float*)d_in[1];
    const int*   ei  = (const int*)d_in[2];
    const float* W1  = (const float*)d_in[3];
    const float* b1  = (const float*)d_in[4];
    const float* W2  = (const float*)d_in[5];
    const float* b2  = (const float*)d_in[6];
    const float* fcw = (const float*)d_in[7];
    const float* fcb = (const float*)d_in[8];
    const float* sig = (const float*)d_in[9];

    int B = in_sizes[1];                 // 4
    int E = in_sizes[2] / 2;             // 320000
    int N = in_sizes[0] / (B * INDIM);   // 20000
    int ntile = N / 4;                   // 5000 (16-row MFMA tiles)

    char* p = (char*)d_ws;
    auto alloc = [&](size_t bytes) { void* r = (void*)p; p += (bytes + 255) & ~(size_t)255; return r; };
    int*    cnt     = (int*)alloc((size_t)N * 4);
    int*    fillcnt = (int*)alloc((size_t)N * 4);
    int*    row_ptr = (int*)alloc((size_t)(N + 1) * 4);
    int*    colA    = (int*)alloc((size_t)E * 4);
    int*    srcA    = (int*)alloc((size_t)E * 4);
    int*    dstA    = (int*)alloc((size_t)E * 4);
    float*  wsrcA   = (float*)alloc((size_t)E * 4);
    float*  dis     = (float*)alloc((size_t)N * 4);
    float*  pooledS = (float*)alloc((size_t)NSH * 512 * 4);
    int*    flag    = (int*)alloc(256);
    uint*   xbf     = (uint*)alloc((size_t)N * 128 * 4);      // 10.25 MB bf16 [n][b][64c]
    uint*   x1      = (uint*)alloc((size_t)N * 4 * 64 * 4);   // 20.5 MB bf16 [r][128c]
    uint*   w1t     = (uint*)alloc((size_t)128 * 32 * 4);     // bf16 [128c][64k]
    uint*   w2t     = (uint*)alloc((size_t)128 * 64 * 4);     // bf16 [128c][128k]
    (void)ws_size;

    int gE = (E + 255) / 256;

    k_init_cast<<<2048, 256, 0, stream>>>(x, W1, W2, ei, xbf, w1t, w2t, cnt, pooledS, flag, N);
    k_edges<<<gE, 256, 0, stream>>>(ei, flag, srcA, dstA, cnt, E);
    k_scan<<<1, 256, 0, stream>>>(cnt, row_ptr, dis, fillcnt, N);
    k_fill<<<gE, 256, 0, stream>>>(srcA, dstA, row_ptr, fillcnt, colA, wsrcA, dis, E);

    k_l1<<<2048, 256, 0, stream>>>(xbf, row_ptr, colA, wsrcA, dis, (const ushort*)w1t, b1, x1, ntile);
    k_l2<<<2048, 256, 0, stream>>>(x1, row_ptr, colA, wsrcA, dis, (const ushort*)w2t, b2, pooledS, ntile, 1.0f / (float)N);

    k_head<<<1, 64, 0, stream>>>(pooledS, af, fcw, fcb, sig, (float*)d_out, B);
}

// Round 5
// 204.306 us; speedup vs baseline: 2.4522x; 1.2045x over previous
//
#include <hip/hip_runtime.h>
#include <math.h>

#define HID 128
#define INDIM 64
#define NSH 32   // pooled shadow copies

typedef unsigned int uint;
typedef unsigned short ushort;
typedef __attribute__((ext_vector_type(8))) short short8;
typedef __attribute__((ext_vector_type(4))) float f32x4;

static __device__ inline float bf2f(uint h) { return __uint_as_float(h << 16); }
static __device__ inline ushort f2bf(float f) {
    uint u = __float_as_uint(f);
    return (ushort)((u + 0x7fff + ((u >> 16) & 1)) >> 16);  // RNE
}
static __device__ inline uint packbf2(float a, float b) {
    return (uint)f2bf(a) | ((uint)f2bf(b) << 16);
}

// ---------------- init + casts + int32/int64 detect ----------------
__global__ __launch_bounds__(256) void k_init_cast(
    const float* __restrict__ x, const float* __restrict__ W1, const float* __restrict__ W2,
    const int* __restrict__ ei,
    uint* __restrict__ xbf, uint* __restrict__ w1t, uint* __restrict__ w2t,
    int* cnt, float* pooledS, int* flag, int N)
{
    int gid = blockIdx.x * 256 + threadIdx.x;
    int stride = gridDim.x * 256;
    // block 0: detect layout (int64 LE: high words of first 256 entries are all 0)
    if (blockIdx.x == 0) {
        __shared__ int sbad;
        if (threadIdx.x == 0) sbad = 0;
        __syncthreads();
        int bad = (ei[2 * threadIdx.x + 1] != 0) ? 1 : 0;
        if (__any(bad) && (threadIdx.x & 63) == 0) atomicOr(&sbad, 1);
        __syncthreads();
        if (threadIdx.x == 0) *flag = sbad;
    }
    int total = N * 128;  // bf16-pairs of xbf
    for (int i = gid; i < total; i += stride) {
        int n = i >> 7, r = i & 127;
        int b = r >> 5, c2 = r & 31;
        const float* s = x + ((size_t)b * N + n) * 64 + c2 * 2;
        xbf[i] = packbf2(s[0], s[1]);
    }
    if (gid < 128 * 32) { int c = gid >> 5, k2 = gid & 31; w1t[gid] = packbf2(W1[(2 * k2) * 128 + c], W1[(2 * k2 + 1) * 128 + c]); }
    if (gid < 128 * 64) { int c = gid >> 6, k2 = gid & 63; w2t[gid] = packbf2(W2[(2 * k2) * 128 + c], W2[(2 * k2 + 1) * 128 + c]); }
    if (gid < N) cnt[gid] = 0;
    if (gid < NSH * 512) pooledS[gid] = 0.f;
}

// extract src/dst + degree count (fused)
__global__ __launch_bounds__(256) void k_edges(const int* __restrict__ ei, const int* __restrict__ flag,
                                               int* __restrict__ src, int* __restrict__ dst,
                                               int* cnt, int E) {
    int e = blockIdx.x * 256 + threadIdx.x;
    if (e >= E) return;
    int s, d;
    if (*flag) { s = ei[e]; d = ei[(size_t)E + e]; }
    else       { s = ei[2 * (size_t)e]; d = ei[2 * (size_t)E + 2 * (size_t)e]; }
    src[e] = s; dst[e] = d;
    atomicAdd(&cnt[d], 1);
}

// ---------------- parallel single-block scan: 1024 threads, shuffle-scan ----------------
// was: 256-thread serial scan, 58.6us (VALUBusy 0.016%) -- hidden top kernel through r4.
__global__ __launch_bounds__(1024) void k_scan(const int* __restrict__ cnt, int* __restrict__ row_ptr,
                                               float* __restrict__ dis, int* __restrict__ fillcnt, int N) {
    __shared__ int wsum[16];
    int t = threadIdx.x;
    int chunk = (N + 1023) >> 10;
    int lo = t * chunk; if (lo > N) lo = N;
    int hi = lo + chunk; if (hi > N) hi = N;
    int s = 0;
#pragma unroll 4
    for (int i = lo; i < hi; i++) s += cnt[i];
    int lane = t & 63, wid = t >> 6;
    int v = s;
#pragma unroll
    for (int d = 1; d < 64; d <<= 1) {
        int u = __shfl_up(v, d);
        if (lane >= d) v += u;
    }
    if (lane == 63) wsum[wid] = v;
    __syncthreads();
    if (wid == 0) {
        int wv = (lane < 16) ? wsum[lane] : 0;
#pragma unroll
        for (int d = 1; d < 16; d <<= 1) {
            int u = __shfl_up(wv, d);
            if (lane >= d) wv += u;
        }
        if (lane < 16) wsum[lane] = wv;   // inclusive wave sums
    }
    __syncthreads();
    int base = (wid > 0 ? wsum[wid - 1] : 0) + (v - s);  // exclusive prefix for this thread
    int acc = base;
#pragma unroll 4
    for (int i = lo; i < hi; i++) {
        row_ptr[i] = acc;
        int c = cnt[i];
        acc += c;
        dis[i] = rsqrtf((float)(c + 1));
        fillcnt[i] = 0;
    }
    if (t == 0) row_ptr[N] = wsum[15];
}

// CSR fill; wsrc[p] = dis[src] precomputed (removes dependent load from gather chain)
__global__ __launch_bounds__(256) void k_fill(const int* __restrict__ src, const int* __restrict__ dst,
                                              const int* __restrict__ row_ptr, int* fillcnt,
                                              int* __restrict__ col, float* __restrict__ wsrc,
                                              const float* __restrict__ dis, int E) {
    int e = blockIdx.x * 256 + threadIdx.x;
    if (e >= E) return;
    int d = dst[e], s = src[e];
    int p = row_ptr[d] + atomicAdd(&fillcnt[d], 1);
    col[p] = s;
    wsrc[p] = dis[s];
}

// ---------------- layer 1 fused: agg(xbf) -> LDS(swz,dbuf) -> MFMA(W1T) -> relu -> x1 bf16 ----------------
__global__ __launch_bounds__(256) void k_l1(
    const uint* __restrict__ xbf, const int* __restrict__ rp, const int* __restrict__ col,
    const float* __restrict__ wsrc, const float* __restrict__ dis,
    const ushort* __restrict__ w1t, const float* __restrict__ b1,
    uint* __restrict__ x1, int ntile)
{
    __shared__ __align__(16) char sX[2 * 2048];   // dbuf: 2 x (16 rows x 128B), XOR-swizzled
    int t = threadIdx.x, w = t >> 6, l = t & 63;
    int g = l >> 4, row = l & 15;
    int ct0 = 2 * w, ct1 = 2 * w + 1;
    short8 wf00 = *(const short8*)(w1t + (ct0 * 16 + row) * 64 + g * 8);
    short8 wf01 = *(const short8*)(w1t + (ct0 * 16 + row) * 64 + 32 + g * 8);
    short8 wf10 = *(const short8*)(w1t + (ct1 * 16 + row) * 64 + g * 8);
    short8 wf11 = *(const short8*)(w1t + (ct1 * 16 + row) * 64 + 32 + g * 8);
    float4 bb0 = *(const float4*)(b1 + ct0 * 16 + g * 4);
    float4 bb1 = *(const float4*)(b1 + ct1 * 16 + g * 4);
    int wrow = w * 4 + g;
    int woff = wrow * 128 + ((((row) >> 1) ^ (wrow & 7)) << 4) + ((row & 1) << 3);
    int roff0 = row * 128 + (((0 + g) ^ (row & 7)) << 4);
    int roff1 = row * 128 + (((4 + g) ^ (row & 7)) << 4);
    const uint2* xr = (const uint2*)xbf;

    int it = 0;
    for (int tile = blockIdx.x; tile < ntile; tile += gridDim.x, it++) {
        int n = tile * 4 + w;
        float dn = dis[n];
        int beg = rp[n], end = rp[n + 1];
        uint2 v = xr[(size_t)n * 64 + l];
        float sl = dn * dn;
        float a0 = bf2f(v.x & 0xffffu) * sl, a1 = bf2f(v.x >> 16) * sl;
        float a2 = bf2f(v.y & 0xffffu) * sl, a3 = bf2f(v.y >> 16) * sl;
        int e = beg;
        for (; e + 3 < end; e += 4) {
            int s0 = col[e], s1 = col[e + 1], s2 = col[e + 2], s3 = col[e + 3];
            float f0 = wsrc[e] * dn, f1 = wsrc[e + 1] * dn, f2 = wsrc[e + 2] * dn, f3 = wsrc[e + 3] * dn;
            uint2 u0 = xr[(size_t)s0 * 64 + l], u1 = xr[(size_t)s1 * 64 + l];
            uint2 u2 = xr[(size_t)s2 * 64 + l], u3 = xr[(size_t)s3 * 64 + l];
            a0 = fmaf(bf2f(u0.x & 0xffffu), f0, a0); a1 = fmaf(bf2f(u0.x >> 16), f0, a1);
            a2 = fmaf(bf2f(u0.y & 0xffffu), f0, a2); a3 = fmaf(bf2f(u0.y >> 16), f0, a3);
            a0 = fmaf(bf2f(u1.x & 0xffffu), f1, a0); a1 = fmaf(bf2f(u1.x >> 16), f1, a1);
            a2 = fmaf(bf2f(u1.y & 0xffffu), f1, a2); a3 = fmaf(bf2f(u1.y >> 16), f1, a3);
            a0 = fmaf(bf2f(u2.x & 0xffffu), f2, a0); a1 = fmaf(bf2f(u2.x >> 16), f2, a1);
            a2 = fmaf(bf2f(u2.y & 0xffffu), f2, a2); a3 = fmaf(bf2f(u2.y >> 16), f2, a3);
            a0 = fmaf(bf2f(u3.x & 0xffffu), f3, a0); a1 = fmaf(bf2f(u3.x >> 16), f3, a1);
            a2 = fmaf(bf2f(u3.y & 0xffffu), f3, a2); a3 = fmaf(bf2f(u3.y >> 16), f3, a3);
        }
        for (; e < end; e++) {
            int s = col[e];
            float f = wsrc[e] * dn;
            uint2 u = xr[(size_t)s * 64 + l];
            a0 = fmaf(bf2f(u.x & 0xffffu), f, a0); a1 = fmaf(bf2f(u.x >> 16), f, a1);
            a2 = fmaf(bf2f(u.y & 0xffffu), f, a2); a3 = fmaf(bf2f(u.y >> 16), f, a3);
        }
        char* wb = sX + (it & 1) * 2048;
        uint2 pk; pk.x = packbf2(a0, a1); pk.y = packbf2(a2, a3);
        *(uint2*)(wb + woff) = pk;
        __syncthreads();
        short8 xf0 = *(const short8*)(wb + roff0);
        short8 xf1 = *(const short8*)(wb + roff1);
        f32x4 acc0 = {0.f, 0.f, 0.f, 0.f}, acc1 = {0.f, 0.f, 0.f, 0.f};
        acc0 = __builtin_amdgcn_mfma_f32_16x16x32_bf16(wf00, xf0, acc0, 0, 0, 0);
        acc0 = __builtin_amdgcn_mfma_f32_16x16x32_bf16(wf01, xf1, acc0, 0, 0, 0);
        acc1 = __builtin_amdgcn_mfma_f32_16x16x32_bf16(wf10, xf0, acc1, 0, 0, 0);
        acc1 = __builtin_amdgcn_mfma_f32_16x16x32_bf16(wf11, xf1, acc1, 0, 0, 0);
        size_t r = (size_t)tile * 16 + row;
        uint2 o0, o1;
        o0.x = packbf2(fmaxf(acc0.x + bb0.x, 0.f), fmaxf(acc0.y + bb0.y, 0.f));
        o0.y = packbf2(fmaxf(acc0.z + bb0.z, 0.f), fmaxf(acc0.w + bb0.w, 0.f));
        o1.x = packbf2(fmaxf(acc1.x + bb1.x, 0.f), fmaxf(acc1.y + bb1.y, 0.f));
        o1.y = packbf2(fmaxf(acc1.z + bb1.z, 0.f), fmaxf(acc1.w + bb1.w, 0.f));
        ((uint2*)x1)[r * 32 + ct0 * 4 + g] = o0;
        ((uint2*)x1)[r * 32 + ct1 * 4 + g] = o1;
    }
}

// ---------------- layer 2 fused: agg(x1) -> LDS(swz,dbuf) -> MFMA(W2T) -> relu -> mean-pool ----------------
__global__ __launch_bounds__(256) void k_l2(
    const uint* __restrict__ x1, const int* __restrict__ rp, const int* __restrict__ col,
    const float* __restrict__ wsrc, const float* __restrict__ dis,
    const ushort* __restrict__ w2t, const float* __restrict__ b2,
    float* __restrict__ pooledS, int ntile, float invN)
{
    __shared__ __align__(16) char sX[2 * 4096];   // dbuf: 2 x (16 rows x 256B), XOR-swizzled
    int t = threadIdx.x, w = t >> 6, l = t & 63;
    int g = l >> 4, row = l & 15;
    int ct0 = 2 * w, ct1 = 2 * w + 1;
    short8 wf0[4], wf1[4];
#pragma unroll
    for (int ks = 0; ks < 4; ks++) {
        wf0[ks] = *(const short8*)(w2t + (ct0 * 16 + row) * 128 + ks * 32 + g * 8);
        wf1[ks] = *(const short8*)(w2t + (ct1 * 16 + row) * 128 + ks * 32 + g * 8);
    }
    float4 bb0 = *(const float4*)(b2 + ct0 * 16 + g * 4);
    float4 bb1 = *(const float4*)(b2 + ct1 * 16 + g * 4);
    int wrow = w * 4 + g;
    int woff = wrow * 256 + (((row) ^ (wrow & 7)) << 4);
    int roff[4];
#pragma unroll
    for (int ks = 0; ks < 4; ks++) roff[ks] = row * 256 + (((ks * 4 + g) ^ (row & 7)) << 4);
    const uint4* xr = (const uint4*)x1;
    float p0[4] = {0.f, 0.f, 0.f, 0.f}, p1[4] = {0.f, 0.f, 0.f, 0.f};

    int it = 0;
    for (int tile = blockIdx.x; tile < ntile; tile += gridDim.x, it++) {
        int n = tile * 4 + w;
        float dn = dis[n];
        int beg = rp[n], end = rp[n + 1];
        uint4 v = xr[(size_t)n * 64 + l];
        float sl = dn * dn;
        float a0 = bf2f(v.x & 0xffffu) * sl, a1 = bf2f(v.x >> 16) * sl;
        float a2 = bf2f(v.y & 0xffffu) * sl, a3 = bf2f(v.y >> 16) * sl;
        float a4 = bf2f(v.z & 0xffffu) * sl, a5 = bf2f(v.z >> 16) * sl;
        float a6 = bf2f(v.w & 0xffffu) * sl, a7 = bf2f(v.w >> 16) * sl;
        int e = beg;
        for (; e + 3 < end; e += 4) {
            int s0 = col[e], s1 = col[e + 1], s2 = col[e + 2], s3 = col[e + 3];
            float f0 = wsrc[e] * dn, f1 = wsrc[e + 1] * dn;
            float f2 = wsrc[e + 2] * dn, f3 = wsrc[e + 3] * dn;
            uint4 u0 = xr[(size_t)s0 * 64 + l], u1 = xr[(size_t)s1 * 64 + l];
            uint4 u2 = xr[(size_t)s2 * 64 + l], u3 = xr[(size_t)s3 * 64 + l];
            a0 = fmaf(bf2f(u0.x & 0xffffu), f0, a0); a1 = fmaf(bf2f(u0.x >> 16), f0, a1);
            a2 = fmaf(bf2f(u0.y & 0xffffu), f0, a2); a3 = fmaf(bf2f(u0.y >> 16), f0, a3);
            a4 = fmaf(bf2f(u0.z & 0xffffu), f0, a4); a5 = fmaf(bf2f(u0.z >> 16), f0, a5);
            a6 = fmaf(bf2f(u0.w & 0xffffu), f0, a6); a7 = fmaf(bf2f(u0.w >> 16), f0, a7);
            a0 = fmaf(bf2f(u1.x & 0xffffu), f1, a0); a1 = fmaf(bf2f(u1.x >> 16), f1, a1);
            a2 = fmaf(bf2f(u1.y & 0xffffu), f1, a2); a3 = fmaf(bf2f(u1.y >> 16), f1, a3);
            a4 = fmaf(bf2f(u1.z & 0xffffu), f1, a4); a5 = fmaf(bf2f(u1.z >> 16), f1, a5);
            a6 = fmaf(bf2f(u1.w & 0xffffu), f1, a6); a7 = fmaf(bf2f(u1.w >> 16), f1, a7);
            a0 = fmaf(bf2f(u2.x & 0xffffu), f2, a0); a1 = fmaf(bf2f(u2.x >> 16), f2, a1);
            a2 = fmaf(bf2f(u2.y & 0xffffu), f2, a2); a3 = fmaf(bf2f(u2.y >> 16), f2, a3);
            a4 = fmaf(bf2f(u2.z & 0xffffu), f2, a4); a5 = fmaf(bf2f(u2.z >> 16), f2, a5);
            a6 = fmaf(bf2f(u2.w & 0xffffu), f2, a6); a7 = fmaf(bf2f(u2.w >> 16), f2, a7);
            a0 = fmaf(bf2f(u3.x & 0xffffu), f3, a0); a1 = fmaf(bf2f(u3.x >> 16), f3, a1);
            a2 = fmaf(bf2f(u3.y & 0xffffu), f3, a2); a3 = fmaf(bf2f(u3.y >> 16), f3, a3);
            a4 = fmaf(bf2f(u3.z & 0xffffu), f3, a4); a5 = fmaf(bf2f(u3.z >> 16), f3, a5);
            a6 = fmaf(bf2f(u3.w & 0xffffu), f3, a6); a7 = fmaf(bf2f(u3.w >> 16), f3, a7);
        }
        for (; e < end; e++) {
            int s = col[e];
            float f = wsrc[e] * dn;
            uint4 u = xr[(size_t)s * 64 + l];
            a0 = fmaf(bf2f(u.x & 0xffffu), f, a0); a1 = fmaf(bf2f(u.x >> 16), f, a1);
            a2 = fmaf(bf2f(u.y & 0xffffu), f, a2); a3 = fmaf(bf2f(u.y >> 16), f, a3);
            a4 = fmaf(bf2f(u.z & 0xffffu), f, a4); a5 = fmaf(bf2f(u.z >> 16), f, a5);
            a6 = fmaf(bf2f(u.w & 0xffffu), f, a6); a7 = fmaf(bf2f(u.w >> 16), f, a7);
        }
        char* wb = sX + (it & 1) * 4096;
        uint4 pk;
        pk.x = packbf2(a0, a1); pk.y = packbf2(a2, a3);
        pk.z = packbf2(a4, a5); pk.w = packbf2(a6, a7);
        *(uint4*)(wb + woff) = pk;
        __syncthreads();
        short8 xf[4];
#pragma unroll
        for (int ks = 0; ks < 4; ks++) xf[ks] = *(const short8*)(wb + roff[ks]);
        f32x4 acc0 = {0.f, 0.f, 0.f, 0.f}, acc1 = {0.f, 0.f, 0.f, 0.f};
#pragma unroll
        for (int ks = 0; ks < 4; ks++) {
            acc0 = __builtin_amdgcn_mfma_f32_16x16x32_bf16(wf0[ks], xf[ks], acc0, 0, 0, 0);
            acc1 = __builtin_amdgcn_mfma_f32_16x16x32_bf16(wf1[ks], xf[ks], acc1, 0, 0, 0);
        }
        p0[0] += fmaxf(acc0.x + bb0.x, 0.f); p0[1] += fmaxf(acc0.y + bb0.y, 0.f);
        p0[2] += fmaxf(acc0.z + bb0.z, 0.f); p0[3] += fmaxf(acc0.w + bb0.w, 0.f);
        p1[0] += fmaxf(acc1.x + bb1.x, 0.f); p1[1] += fmaxf(acc1.y + bb1.y, 0.f);
        p1[2] += fmaxf(acc1.z + bb1.z, 0.f); p1[3] += fmaxf(acc1.w + bb1.w, 0.f);
    }
    // rows with same batch b = row&3 live in lanes l, l^4, l^8
#pragma unroll
    for (int i = 0; i < 4; i++) {
        p0[i] += __shfl_xor(p0[i], 4); p0[i] += __shfl_xor(p0[i], 8);
        p1[i] += __shfl_xor(p1[i], 4); p1[i] += __shfl_xor(p1[i], 8);
    }
    if ((l & 12) == 0) {
        int b = l & 3;
        float* pd = pooledS + (size_t)(blockIdx.x & (NSH - 1)) * 512 + b * 128;
#pragma unroll
        for (int i = 0; i < 4; i++) {
            atomicAdd(&pd[ct0 * 16 + g * 4 + i], p0[i] * invN);
            atomicAdd(&pd[ct1 * 16 + g * 4 + i], p1[i] * invN);
        }
    }
}

// ---------------- head ----------------
__global__ __launch_bounds__(64) void k_head(const float* __restrict__ pooledS, const float* __restrict__ af,
                                             const float* __restrict__ fcw, const float* __restrict__ fcb,
                                             const float* __restrict__ sig, float* __restrict__ out, int B) {
    int t = threadIdx.x;
    if (t >= B * 16) return;
    int b = t >> 4, o = t & 15;
    float acc = fcb[o];
    for (int c = 0; c < HID; c++) {
        float pc = 0.f;
        for (int s = 0; s < NSH; s++) pc += pooledS[s * 512 + b * 128 + c];
        acc = fmaf(pc, fcw[c * 16 + o], acc);
    }
    acc = fmaf(af[b], fcw[HID * 16 + o], acc);
    out[b * 16 + o] = acc;
    out[B * 16 + b * 16 + o] = expf(sig[o]);
}

// ---------------- launch ----------------

extern "C" void kernel_launch(void* const* d_in, const int* in_sizes, int n_in,
                              void* d_out, int out_size, void* d_ws, size_t ws_size,
                              hipStream_t stream) {
    const float* x   = (const float*)d_in[0];
    const float* af  = (const float*)d_in[1];
    const int*   ei  = (const int*)d_in[2];
    const float* W1  = (const float*)d_in[3];
    const float* b1  = (const float*)d_in[4];
    const float* W2  = (const float*)d_in[5];
    const float* b2  = (const float*)d_in[6];
    const float* fcw = (const float*)d_in[7];
    const float* fcb = (const float*)d_in[8];
    const float* sig = (const float*)d_in[9];

    int B = in_sizes[1];                 // 4
    int E = in_sizes[2] / 2;             // 320000
    int N = in_sizes[0] / (B * INDIM);   // 20000
    int ntile = N / 4;                   // 5000 (16-row MFMA tiles)

    char* p = (char*)d_ws;
    auto alloc = [&](size_t bytes) { void* r = (void*)p; p += (bytes + 255) & ~(size_t)255; return r; };
    int*    cnt     = (int*)alloc((size_t)N * 4);
    int*    fillcnt = (int*)alloc((size_t)N * 4);
    int*    row_ptr = (int*)alloc((size_t)(N + 1) * 4);
    int*    colA    = (int*)alloc((size_t)E * 4);
    int*    srcA    = (int*)alloc((size_t)E * 4);
    int*    dstA    = (int*)alloc((size_t)E * 4);
    float*  wsrcA   = (float*)alloc((size_t)E * 4);
    float*  dis     = (float*)alloc((size_t)N * 4);
    float*  pooledS = (float*)alloc((size_t)NSH * 512 * 4);
    int*    flag    = (int*)alloc(256);
    uint*   xbf     = (uint*)alloc((size_t)N * 128 * 4);      // 10.25 MB bf16 [n][b][64c]
    uint*   x1      = (uint*)alloc((size_t)N * 4 * 64 * 4);   // 20.5 MB bf16 [r][128c]
    uint*   w1t     = (uint*)alloc((size_t)128 * 32 * 4);     // bf16 [128c][64k]
    uint*   w2t     = (uint*)alloc((size_t)128 * 64 * 4);     // bf16 [128c][128k]
    (void)ws_size;

    int gE = (E + 255) / 256;

    k_init_cast<<<2048, 256, 0, stream>>>(x, W1, W2, ei, xbf, w1t, w2t, cnt, pooledS, flag, N);
    k_edges<<<gE, 256, 0, stream>>>(ei, flag, srcA, dstA, cnt, E);
    k_scan<<<1, 1024, 0, stream>>>(cnt, row_ptr, dis, fillcnt, N);
    k_fill<<<gE, 256, 0, stream>>>(srcA, dstA, row_ptr, fillcnt, colA, wsrcA, dis, E);

    k_l1<<<2048, 256, 0, stream>>>(xbf, row_ptr, colA, wsrcA, dis, (const ushort*)w1t, b1, x1, ntile);
    k_l2<<<2048, 256, 0, stream>>>(x1, row_ptr, colA, wsrcA, dis, (const ushort*)w2t, b2, pooledS, ntile, 1.0f / (float)N);

    k_head<<<1, 64, 0, stream>>>(pooledS, af, fcw, fcb, sig, (float*)d_out, B);
}

// Round 6
// 179.655 us; speedup vs baseline: 2.7887x; 1.1372x over previous
//
#include <hip/hip_runtime.h>
#include <math.h>

#define HID 128
#define INDIM 64
#define NSH 64   // pooled shadow copies

typedef unsigned int uint;
typedef unsigned short ushort;
typedef __attribute__((ext_vector_type(8))) short short8;
typedef __attribute__((ext_vector_type(4))) float f32x4;

static __device__ inline float bf2f(uint h) { return __uint_as_float(h << 16); }
static __device__ inline ushort f2bf(float f) {
    uint u = __float_as_uint(f);
    return (ushort)((u + 0x7fff + ((u >> 16) & 1)) >> 16);  // RNE
}
static __device__ inline uint packbf2(float a, float b) {
    return (uint)f2bf(a) | ((uint)f2bf(b) << 16);
}
static __device__ inline int imin(int a, int b) { return a < b ? a : b; }

static __device__ inline void init8(float* a, uint4 v, float sl) {
    a[0] = bf2f(v.x & 0xffffu) * sl; a[1] = bf2f(v.x >> 16) * sl;
    a[2] = bf2f(v.y & 0xffffu) * sl; a[3] = bf2f(v.y >> 16) * sl;
    a[4] = bf2f(v.z & 0xffffu) * sl; a[5] = bf2f(v.z >> 16) * sl;
    a[6] = bf2f(v.w & 0xffffu) * sl; a[7] = bf2f(v.w >> 16) * sl;
}
static __device__ inline void acc8(float* a, uint4 u, float f) {
    a[0] = fmaf(bf2f(u.x & 0xffffu), f, a[0]); a[1] = fmaf(bf2f(u.x >> 16), f, a[1]);
    a[2] = fmaf(bf2f(u.y & 0xffffu), f, a[2]); a[3] = fmaf(bf2f(u.y >> 16), f, a[3]);
    a[4] = fmaf(bf2f(u.z & 0xffffu), f, a[4]); a[5] = fmaf(bf2f(u.z >> 16), f, a[5]);
    a[6] = fmaf(bf2f(u.w & 0xffffu), f, a[6]); a[7] = fmaf(bf2f(u.w >> 16), f, a[7]);
}
static __device__ inline void init4(float* a, uint2 v, float sl) {
    a[0] = bf2f(v.x & 0xffffu) * sl; a[1] = bf2f(v.x >> 16) * sl;
    a[2] = bf2f(v.y & 0xffffu) * sl; a[3] = bf2f(v.y >> 16) * sl;
}
static __device__ inline void acc4(float* a, uint2 u, float f) {
    a[0] = fmaf(bf2f(u.x & 0xffffu), f, a[0]); a[1] = fmaf(bf2f(u.x >> 16), f, a[1]);
    a[2] = fmaf(bf2f(u.y & 0xffffu), f, a[2]); a[3] = fmaf(bf2f(u.y >> 16), f, a[3]);
}

// ---------------- init + casts + int32/int64 detect ----------------
__global__ __launch_bounds__(256) void k_init_cast(
    const float* __restrict__ x, const float* __restrict__ W1, const float* __restrict__ W2,
    const int* __restrict__ ei,
    uint* __restrict__ xbf, uint* __restrict__ w1t, uint* __restrict__ w2t,
    int* cnt, float* pooledS, int* flag, int N)
{
    int gid = blockIdx.x * 256 + threadIdx.x;
    int stride = gridDim.x * 256;
    if (blockIdx.x == 0) {
        __shared__ int sbad;
        if (threadIdx.x == 0) sbad = 0;
        __syncthreads();
        int bad = (ei[2 * threadIdx.x + 1] != 0) ? 1 : 0;
        if (__any(bad) && (threadIdx.x & 63) == 0) atomicOr(&sbad, 1);
        __syncthreads();
        if (threadIdx.x == 0) *flag = sbad;
    }
    int total = N * 128;  // bf16-pairs of xbf
    for (int i = gid; i < total; i += stride) {
        int n = i >> 7, r = i & 127;
        int b = r >> 5, c2 = r & 31;
        const float* s = x + ((size_t)b * N + n) * 64 + c2 * 2;
        xbf[i] = packbf2(s[0], s[1]);
    }
    if (gid < 128 * 32) { int c = gid >> 5, k2 = gid & 31; w1t[gid] = packbf2(W1[(2 * k2) * 128 + c], W1[(2 * k2 + 1) * 128 + c]); }
    if (gid < 128 * 64) { int c = gid >> 6, k2 = gid & 63; w2t[gid] = packbf2(W2[(2 * k2) * 128 + c], W2[(2 * k2 + 1) * 128 + c]); }
    if (gid < N) cnt[gid] = 0;
    if (gid < NSH * 512) pooledS[gid] = 0.f;
}

// extract src/dst + degree count (fused)
__global__ __launch_bounds__(256) void k_edges(const int* __restrict__ ei, const int* __restrict__ flag,
                                               int* __restrict__ src, int* __restrict__ dst,
                                               int* cnt, int E) {
    int e = blockIdx.x * 256 + threadIdx.x;
    if (e >= E) return;
    int s, d;
    if (*flag) { s = ei[e]; d = ei[(size_t)E + e]; }
    else       { s = ei[2 * (size_t)e]; d = ei[2 * (size_t)E + 2 * (size_t)e]; }
    src[e] = s; dst[e] = d;
    atomicAdd(&cnt[d], 1);
}

// ---------------- parallel single-block scan: 1024 threads, shuffle-scan ----------------
__global__ __launch_bounds__(1024) void k_scan(const int* __restrict__ cnt, int* __restrict__ row_ptr,
                                               float* __restrict__ dis, int* __restrict__ fillcnt, int N) {
    __shared__ int wsum[16];
    int t = threadIdx.x;
    int chunk = (N + 1023) >> 10;
    int lo = t * chunk; if (lo > N) lo = N;
    int hi = lo + chunk; if (hi > N) hi = N;
    int s = 0;
#pragma unroll 4
    for (int i = lo; i < hi; i++) s += cnt[i];
    int lane = t & 63, wid = t >> 6;
    int v = s;
#pragma unroll
    for (int d = 1; d < 64; d <<= 1) {
        int u = __shfl_up(v, d);
        if (lane >= d) v += u;
    }
    if (lane == 63) wsum[wid] = v;
    __syncthreads();
    if (wid == 0) {
        int wv = (lane < 16) ? wsum[lane] : 0;
#pragma unroll
        for (int d = 1; d < 16; d <<= 1) {
            int u = __shfl_up(wv, d);
            if (lane >= d) wv += u;
        }
        if (lane < 16) wsum[lane] = wv;
    }
    __syncthreads();
    int base = (wid > 0 ? wsum[wid - 1] : 0) + (v - s);
    int acc = base;
#pragma unroll 4
    for (int i = lo; i < hi; i++) {
        row_ptr[i] = acc;
        int c = cnt[i];
        acc += c;
        dis[i] = rsqrtf((float)(c + 1));
        fillcnt[i] = 0;
    }
    if (t == 0) row_ptr[N] = wsum[15];
}

// CSR fill; wsrc[p] = dis[src] precomputed
__global__ __launch_bounds__(256) void k_fill(const int* __restrict__ src, const int* __restrict__ dst,
                                              const int* __restrict__ row_ptr, int* fillcnt,
                                              int* __restrict__ col, float* __restrict__ wsrc,
                                              const float* __restrict__ dis, int E) {
    int e = blockIdx.x * 256 + threadIdx.x;
    if (e >= E) return;
    int d = dst[e], s = src[e];
    int p = row_ptr[d] + atomicAdd(&fillcnt[d], 1);
    col[p] = s;
    wsrc[p] = dis[s];
}

// ---------------- layer 1: wave-independent tile (4 nodes x 4 batches), no barriers ----------------
__global__ __launch_bounds__(256, 4) void k_l1(
    const uint* __restrict__ xbf, const int* __restrict__ rp, const int* __restrict__ col,
    const float* __restrict__ wsrc, const float* __restrict__ dis,
    const uint* __restrict__ w1t, const float* __restrict__ b1,
    uint* __restrict__ x1, int ntile)
{
    __shared__ __align__(16) char sW[16384];      // W1T swizzled: 128c x 64k bf16
    __shared__ __align__(16) char sXa[4][2048];   // wave-private 16 rows x 128B
    int t = threadIdx.x, w = t >> 6, l = t & 63;
    int g = l >> 4, row = l & 15;
    for (int i = t; i < 1024; i += 256) {
        int c = i >> 3, ch = i & 7;
        *(uint4*)(sW + c * 128 + ((ch ^ (c & 7)) << 4)) = *(const uint4*)(w1t + c * 32 + ch * 4);
    }
    __syncthreads();  // only barrier in kernel
    int tile = blockIdx.x * 4 + w;
    if (tile >= ntile) return;
    char* sX = sXa[w];
    const uint2* xr = (const uint2*)xbf;

    int n0 = tile * 4;
    int r0 = rp[n0], r1 = rp[n0 + 1], r2 = rp[n0 + 2], r3 = rp[n0 + 3], r4 = rp[n0 + 4];
    int e0 = r0, e1 = r1, e2 = r2, e3 = r3;
    float dn0 = dis[n0], dn1 = dis[n0 + 1], dn2 = dis[n0 + 2], dn3 = dis[n0 + 3];
    float ac0[4], ac1[4], ac2[4], ac3[4];
    init4(ac0, xr[(size_t)n0 * 64 + l], dn0 * dn0);
    init4(ac1, xr[(size_t)(n0 + 1) * 64 + l], dn1 * dn1);
    init4(ac2, xr[(size_t)(n0 + 2) * 64 + l], dn2 * dn2);
    init4(ac3, xr[(size_t)(n0 + 3) * 64 + l], dn3 * dn3);

#define A2(j) do { \
    int c0_ = col[e##j], c1_ = col[e##j + 1]; \
    float f0_ = wsrc[e##j] * dn##j, f1_ = wsrc[e##j + 1] * dn##j; \
    uint2 u0_ = xr[(size_t)c0_ * 64 + l], u1_ = xr[(size_t)c1_ * 64 + l]; \
    acc4(ac##j, u0_, f0_); acc4(ac##j, u1_, f1_); e##j += 2; } while (0)
#define A1(j) do { \
    int c0_ = col[e##j]; float f0_ = wsrc[e##j] * dn##j; \
    uint2 u0_ = xr[(size_t)c0_ * 64 + l]; acc4(ac##j, u0_, f0_); e##j += 1; } while (0)

    int m = imin(imin(r1 - e0, r2 - e1), imin(r3 - e2, r4 - e3)) >> 1;
    for (int it = 0; it < m; it++) { A2(0); A2(1); A2(2); A2(3); }
    int p01 = imin(r1 - e0, r2 - e1) >> 1;
    for (int it = 0; it < p01; it++) { A2(0); A2(1); }
    int p23 = imin(r3 - e2, r4 - e3) >> 1;
    for (int it = 0; it < p23; it++) { A2(2); A2(3); }
    while (e0 + 1 < r1) A2(0);
    if (e0 < r1) A1(0);
    while (e1 + 1 < r2) A2(1);
    if (e1 < r2) A1(1);
    while (e2 + 1 < r3) A2(2);
    if (e2 < r3) A1(2);
    while (e3 + 1 < r4) A2(3);
    if (e3 < r4) A1(3);
#undef A2
#undef A1

    // write 4 rows (8B each, half-slot swizzle) -- wave-private, no barrier
    {
        uint2 pk;
        pk.x = packbf2(ac0[0], ac0[1]); pk.y = packbf2(ac0[2], ac0[3]);
        int wr = g;
        *(uint2*)(sX + wr * 128 + (((row >> 1) ^ (wr & 7)) << 4) + ((row & 1) << 3)) = pk;
        pk.x = packbf2(ac1[0], ac1[1]); pk.y = packbf2(ac1[2], ac1[3]);
        wr = 4 + g;
        *(uint2*)(sX + wr * 128 + (((row >> 1) ^ (wr & 7)) << 4) + ((row & 1) << 3)) = pk;
        pk.x = packbf2(ac2[0], ac2[1]); pk.y = packbf2(ac2[2], ac2[3]);
        wr = 8 + g;
        *(uint2*)(sX + wr * 128 + (((row >> 1) ^ (wr & 7)) << 4) + ((row & 1) << 3)) = pk;
        pk.x = packbf2(ac3[0], ac3[1]); pk.y = packbf2(ac3[2], ac3[3]);
        wr = 12 + g;
        *(uint2*)(sX + wr * 128 + (((row >> 1) ^ (wr & 7)) << 4) + ((row & 1) << 3)) = pk;
    }
    int ro0 = row * 128 + ((g ^ (row & 7)) << 4);
    int ro1 = row * 128 + (((4 + g) ^ (row & 7)) << 4);
    short8 xf0 = *(const short8*)(sX + ro0);
    short8 xf1 = *(const short8*)(sX + ro1);
    size_t rbase = ((size_t)tile * 16 + row) * 32;
#pragma unroll
    for (int q = 0; q < 8; q++) {
        f32x4 a = {0.f, 0.f, 0.f, 0.f};
        const char* wb = sW + q * 2048;
        a = __builtin_amdgcn_mfma_f32_16x16x32_bf16(*(const short8*)(wb + ro0), xf0, a, 0, 0, 0);
        a = __builtin_amdgcn_mfma_f32_16x16x32_bf16(*(const short8*)(wb + ro1), xf1, a, 0, 0, 0);
        float4 bb = *(const float4*)(b1 + q * 16 + g * 4);
        uint2 o;
        o.x = packbf2(fmaxf(a.x + bb.x, 0.f), fmaxf(a.y + bb.y, 0.f));
        o.y = packbf2(fmaxf(a.z + bb.z, 0.f), fmaxf(a.w + bb.w, 0.f));
        ((uint2*)x1)[rbase + q * 4 + g] = o;
    }
}

// ---------------- layer 2: wave-independent tile + MFMA + relu + mean-pool, no barriers ----------------
__global__ __launch_bounds__(256, 3) void k_l2(
    const uint* __restrict__ x1, const int* __restrict__ rp, const int* __restrict__ col,
    const float* __restrict__ wsrc, const float* __restrict__ dis,
    const uint* __restrict__ w2t, const float* __restrict__ b2,
    float* __restrict__ pooledS, int ntile, float invN)
{
    __shared__ __align__(16) char sW[32768];      // W2T swizzled: 128c x 128k bf16
    __shared__ __align__(16) char sXa[4][4096];   // wave-private 16 rows x 256B
    int t = threadIdx.x, w = t >> 6, l = t & 63;
    int g = l >> 4, row = l & 15;
    for (int i = t; i < 2048; i += 256) {
        int c = i >> 4, ch = i & 15;
        *(uint4*)(sW + c * 256 + ((ch ^ (c & 7)) << 4)) = *(const uint4*)(w2t + c * 64 + ch * 4);
    }
    __syncthreads();  // only barrier in kernel
    int tile = blockIdx.x * 4 + w;
    if (tile >= ntile) return;
    char* sX = sXa[w];
    const uint4* xr = (const uint4*)x1;

    int n0 = tile * 4;
    int r0 = rp[n0], r1 = rp[n0 + 1], r2 = rp[n0 + 2], r3 = rp[n0 + 3], r4 = rp[n0 + 4];
    int e0 = r0, e1 = r1, e2 = r2, e3 = r3;
    float dn0 = dis[n0], dn1 = dis[n0 + 1], dn2 = dis[n0 + 2], dn3 = dis[n0 + 3];
    float ac0[8], ac1[8], ac2[8], ac3[8];
    init8(ac0, xr[(size_t)n0 * 64 + l], dn0 * dn0);
    init8(ac1, xr[(size_t)(n0 + 1) * 64 + l], dn1 * dn1);
    init8(ac2, xr[(size_t)(n0 + 2) * 64 + l], dn2 * dn2);
    init8(ac3, xr[(size_t)(n0 + 3) * 64 + l], dn3 * dn3);

#define B2(j) do { \
    int c0_ = col[e##j], c1_ = col[e##j + 1]; \
    float f0_ = wsrc[e##j] * dn##j, f1_ = wsrc[e##j + 1] * dn##j; \
    uint4 u0_ = xr[(size_t)c0_ * 64 + l], u1_ = xr[(size_t)c1_ * 64 + l]; \
    acc8(ac##j, u0_, f0_); acc8(ac##j, u1_, f1_); e##j += 2; } while (0)
#define B1(j) do { \
    int c0_ = col[e##j]; float f0_ = wsrc[e##j] * dn##j; \
    uint4 u0_ = xr[(size_t)c0_ * 64 + l]; acc8(ac##j, u0_, f0_); e##j += 1; } while (0)

    int m = imin(imin(r1 - e0, r2 - e1), imin(r3 - e2, r4 - e3)) >> 1;
    for (int it = 0; it < m; it++) { B2(0); B2(1); B2(2); B2(3); }
    int p01 = imin(r1 - e0, r2 - e1) >> 1;
    for (int it = 0; it < p01; it++) { B2(0); B2(1); }
    int p23 = imin(r3 - e2, r4 - e3) >> 1;
    for (int it = 0; it < p23; it++) { B2(2); B2(3); }
    while (e0 + 1 < r1) B2(0);
    if (e0 < r1) B1(0);
    while (e1 + 1 < r2) B2(1);
    if (e1 < r2) B1(1);
    while (e2 + 1 < r3) B2(2);
    if (e2 < r3) B1(2);
    while (e3 + 1 < r4) B2(3);
    if (e3 < r4) B1(3);
#undef B2
#undef B1

    // write 4 rows (16B each, swizzled) -- wave-private
    {
        uint4 pk;
        pk.x = packbf2(ac0[0], ac0[1]); pk.y = packbf2(ac0[2], ac0[3]);
        pk.z = packbf2(ac0[4], ac0[5]); pk.w = packbf2(ac0[6], ac0[7]);
        int wr = g;
        *(uint4*)(sX + wr * 256 + ((row ^ (wr & 7)) << 4)) = pk;
        pk.x = packbf2(ac1[0], ac1[1]); pk.y = packbf2(ac1[2], ac1[3]);
        pk.z = packbf2(ac1[4], ac1[5]); pk.w = packbf2(ac1[6], ac1[7]);
        wr = 4 + g;
        *(uint4*)(sX + wr * 256 + ((row ^ (wr & 7)) << 4)) = pk;
        pk.x = packbf2(ac2[0], ac2[1]); pk.y = packbf2(ac2[2], ac2[3]);
        pk.z = packbf2(ac2[4], ac2[5]); pk.w = packbf2(ac2[6], ac2[7]);
        wr = 8 + g;
        *(uint4*)(sX + wr * 256 + ((row ^ (wr & 7)) << 4)) = pk;
        pk.x = packbf2(ac3[0], ac3[1]); pk.y = packbf2(ac3[2], ac3[3]);
        pk.z = packbf2(ac3[4], ac3[5]); pk.w = packbf2(ac3[6], ac3[7]);
        wr = 12 + g;
        *(uint4*)(sX + wr * 256 + ((row ^ (wr & 7)) << 4)) = pk;
    }
    int ro0 = row * 256 + ((g ^ (row & 7)) << 4);
    int ro1 = row * 256 + (((4 + g) ^ (row & 7)) << 4);
    int ro2 = row * 256 + (((8 + g) ^ (row & 7)) << 4);
    int ro3 = row * 256 + (((12 + g) ^ (row & 7)) << 4);
    short8 xf0 = *(const short8*)(sX + ro0);
    short8 xf1 = *(const short8*)(sX + ro1);
    short8 xf2 = *(const short8*)(sX + ro2);
    short8 xf3 = *(const short8*)(sX + ro3);
#pragma unroll
    for (int q = 0; q < 8; q++) {
        f32x4 a = {0.f, 0.f, 0.f, 0.f};
        const char* wb = sW + q * 4096;
        a = __builtin_amdgcn_mfma_f32_16x16x32_bf16(*(const short8*)(wb + ro0), xf0, a, 0, 0, 0);
        a = __builtin_amdgcn_mfma_f32_16x16x32_bf16(*(const short8*)(wb + ro1), xf1, a, 0, 0, 0);
        a = __builtin_amdgcn_mfma_f32_16x16x32_bf16(*(const short8*)(wb + ro2), xf2, a, 0, 0, 0);
        a = __builtin_amdgcn_mfma_f32_16x16x32_bf16(*(const short8*)(wb + ro3), xf3, a, 0, 0, 0);
        float4 bb = *(const float4*)(b2 + q * 16 + g * 4);
        float v0 = fmaxf(a.x + bb.x, 0.f);
        float v1 = fmaxf(a.y + bb.y, 0.f);
        float v2 = fmaxf(a.z + bb.z, 0.f);
        float v3 = fmaxf(a.w + bb.w, 0.f);
        // sum over the 4 nodes (tile-row bits 2..3) for each batch (bits 0..1)
        v0 += __shfl_xor(v0, 4); v0 += __shfl_xor(v0, 8);
        v1 += __shfl_xor(v1, 4); v1 += __shfl_xor(v1, 8);
        v2 += __shfl_xor(v2, 4); v2 += __shfl_xor(v2, 8);
        v3 += __shfl_xor(v3, 4); v3 += __shfl_xor(v3, 8);
        if ((l & 12) == 0) {
            float* pd = pooledS + (size_t)(tile & (NSH - 1)) * 512 + (l & 3) * 128 + q * 16 + g * 4;
            atomicAdd(pd + 0, v0 * invN);
            atomicAdd(pd + 1, v1 * invN);
            atomicAdd(pd + 2, v2 * invN);
            atomicAdd(pd + 3, v3 * invN);
        }
    }
}

// ---------------- head: parallel shadow reduce + GEMV ----------------
__global__ __launch_bounds__(512) void k_head(const float* __restrict__ pooledS, const float* __restrict__ af,
                                              const float* __restrict__ fcw, const float* __restrict__ fcb,
                                              const float* __restrict__ sig, float* __restrict__ out, int B) {
    __shared__ float pool[512];
    int t = threadIdx.x;
    float s = 0.f;
#pragma unroll 8
    for (int sh = 0; sh < NSH; sh++) s += pooledS[sh * 512 + t];
    pool[t] = s;
    __syncthreads();
    if (t >= B * 16) return;
    int b = t >> 4, o = t & 15;
    float acc = fcb[o];
    for (int c = 0; c < HID; c++) acc = fmaf(pool[b * 128 + c], fcw[c * 16 + o], acc);
    acc = fmaf(af[b], fcw[HID * 16 + o], acc);
    out[t] = acc;
    out[B * 16 + t] = expf(sig[o]);
}

// ---------------- launch ----------------

extern "C" void kernel_launch(void* const* d_in, const int* in_sizes, int n_in,
                              void* d_out, int out_size, void* d_ws, size_t ws_size,
                              hipStream_t stream) {
    const float* x   = (const float*)d_in[0];
    const float* af  = (const float*)d_in[1];
    const int*   ei  = (const int*)d_in[2];
    const float* W1  = (const float*)d_in[3];
    const float* b1  = (const float*)d_in[4];
    const float* W2  = (const float*)d_in[5];
    const float* b2  = (const float*)d_in[6];
    const float* fcw = (const float*)d_in[7];
    const float* fcb = (const float*)d_in[8];
    const float* sig = (const float*)d_in[9];

    int B = in_sizes[1];                 // 4
    int E = in_sizes[2] / 2;             // 320000
    int N = in_sizes[0] / (B * INDIM);   // 20000
    int ntile = N / 4;                   // 5000

    char* p = (char*)d_ws;
    auto alloc = [&](size_t bytes) { void* r = (void*)p; p += (bytes + 255) & ~(size_t)255; return r; };
    int*    cnt     = (int*)alloc((size_t)N * 4);
    int*    fillcnt = (int*)alloc((size_t)N * 4);
    int*    row_ptr = (int*)alloc((size_t)(N + 1) * 4);
    int*    colA    = (int*)alloc((size_t)E * 4);
    int*    srcA    = (int*)alloc((size_t)E * 4);
    int*    dstA    = (int*)alloc((size_t)E * 4);
    float*  wsrcA   = (float*)alloc((size_t)E * 4);
    float*  dis     = (float*)alloc((size_t)N * 4);
    float*  pooledS = (float*)alloc((size_t)NSH * 512 * 4);
    int*    flag    = (int*)alloc(256);
    uint*   xbf     = (uint*)alloc((size_t)N * 128 * 4);      // bf16 [n][4b][64c]
    uint*   x1      = (uint*)alloc((size_t)N * 4 * 64 * 4);   // bf16 [node*4+b][128c]
    uint*   w1t     = (uint*)alloc((size_t)128 * 32 * 4);     // bf16 [128c][64k]
    uint*   w2t     = (uint*)alloc((size_t)128 * 64 * 4);     // bf16 [128c][128k]
    (void)ws_size;

    int gE = (E + 255) / 256;
    int gL = (ntile + 3) / 4;  // one wave per 16-row tile

    k_init_cast<<<2048, 256, 0, stream>>>(x, W1, W2, ei, xbf, w1t, w2t, cnt, pooledS, flag, N);
    k_edges<<<gE, 256, 0, stream>>>(ei, flag, srcA, dstA, cnt, E);
    k_scan<<<1, 1024, 0, stream>>>(cnt, row_ptr, dis, fillcnt, N);
    k_fill<<<gE, 256, 0, stream>>>(srcA, dstA, row_ptr, fillcnt, colA, wsrcA, dis, E);

    k_l1<<<gL, 256, 0, stream>>>(xbf, row_ptr, colA, wsrcA, dis, w1t, b1, x1, ntile);
    k_l2<<<gL, 256, 0, stream>>>(x1, row_ptr, colA, wsrcA, dis, w2t, b2, pooledS, ntile, 1.0f / (float)N);

    k_head<<<1, 512, 0, stream>>>(pooledS, af, fcw, fcb, sig, (float*)d_out, B);
}